// Round 10
// baseline (2582.443 us; speedup 1.0000x reference)
//
#include <hip/hip_runtime.h>
#include <hip/hip_bf16.h>
#include <math.h>
#include <float.h>

#define BB   4
#define N1   1024
#define N2   4096
#define CIN  512
#define CC   256
#define DM   256
#define KNNK 16

// round-to-nearest-even fp32 -> bf16 -> fp32
__device__ __forceinline__ float bf16r(float x) {
    return __bfloat162float(__float2bfloat16(x));
}

// ---------------------------------------------------------------------------
// bf16-precision GEMM: operands bf16 (W always rounded at load; X rounded iff
// RX i.e. it's a raw network input), fp32 accumulation, bf16-rounded
// materializations: mm -> (+bias) -> (*scale) -> relu -> (+resid).
// Block: 256 threads (one per column) x 16 rows.
// ---------------------------------------------------------------------------
template<int KD, bool RELU, bool RX>
__global__ __launch_bounds__(256) void gemm16(
    const float* __restrict__ X, const float* __restrict__ W,
    const float* __restrict__ bias, const float* __restrict__ resid,
    float scale, float* __restrict__ Y)
{
    const int c = threadIdx.x;
    const size_t row0 = (size_t)blockIdx.x * 16;
    const float* Xp = X + row0 * KD;
    float acc[16];
#pragma unroll
    for (int r = 0; r < 16; ++r) acc[r] = 0.f;
    for (int j = 0; j < KD; ++j) {
        float w = bf16r(W[(size_t)j * 256 + c]);
#pragma unroll
        for (int r = 0; r < 16; ++r) {
            float xv = Xp[(size_t)r * KD + j];
            if (RX) xv = bf16r(xv);
            acc[r] = fmaf(xv, w, acc[r]);
        }
    }
    float bb = bias ? bias[c] : 0.f;   // biases are all zeros
#pragma unroll
    for (int r = 0; r < 16; ++r) {
        float v = bf16r(acc[r]);           // matmul materialized (bf16)
        v = bf16r(v + bb);                 // +bias (nop for 0)
        if (scale != 1.f) v = bf16r(v * scale);  // *bn (sub-half-ulp: nop)
        if (RELU) v = fmaxf(v, 0.f);
        if (resid) v = bf16r(v + resid[(row0 + r) * 256 + c]);
        Y[(row0 + r) * 256 + c] = v;
    }
}

// ---- faithful fp32 distance (selection path runs on RAW fp32 coords) ------
__device__ __forceinline__ float norm2_ref(float x, float y, float z) {
    return __fadd_rn(__fadd_rn(__fmul_rn(x, x), __fmul_rn(y, y)), __fmul_rn(z, z));
}
__device__ __forceinline__ float dist_ref(float sa, float nb,
                                          float ax, float ay, float az,
                                          float bx, float by, float bz) {
    float dot = __fadd_rn(__fadd_rn(__fmul_rn(ax, bx), __fmul_rn(ay, by)),
                          __fmul_rn(az, bz));
    return __fsub_rn(__fadd_rn(sa, nb), __fmul_rn(2.f, dot));
}

// ---------------------------------------------------------------------------
// 3-NN (fp32 coords/distances, stable lower-index ties), fp32 weights.
// ---------------------------------------------------------------------------
__global__ __launch_bounds__(256) void nn3_kernel(
    const float* __restrict__ xyz1, const float* __restrict__ xyz2,
    int* __restrict__ idx3, float* __restrict__ w3)
{
    const int b = blockIdx.x >> 4;
    const int n = ((blockIdx.x & 15) << 8) + threadIdx.x;
    __shared__ float sx[N1], sy[N1], sz[N1], snb[N1];
    for (int i = threadIdx.x; i < N1; i += 256) {
        const float* p = xyz1 + ((size_t)b * N1 + i) * 3;
        float x = p[0], y = p[1], z = p[2];
        sx[i] = x; sy[i] = y; sz[i] = z;
        snb[i] = norm2_ref(x, y, z);
    }
    __syncthreads();
    const float* pq = xyz2 + ((size_t)b * N2 + n) * 3;
    const float ax = pq[0], ay = pq[1], az = pq[2];
    const float sa = norm2_ref(ax, ay, az);
    float d0 = FLT_MAX, d1 = FLT_MAX, d2 = FLT_MAX;
    int i0 = 0, i1 = 0, i2 = 0;
    for (int j = 0; j < N1; ++j) {
        float dist = dist_ref(sa, snb[j], ax, ay, az, sx[j], sy[j], sz[j]);
        if (dist < d2) {
            if (dist < d1) {
                d2 = d1; i2 = i1;
                if (dist < d0) { d1 = d0; i1 = i0; d0 = dist; i0 = j; }
                else           { d1 = dist; i1 = j; }
            } else { d2 = dist; i2 = j; }
        }
    }
    float r0 = __fdiv_rn(1.f, __fadd_rn(d0, 1e-8f));
    float r1 = __fdiv_rn(1.f, __fadd_rn(d1, 1e-8f));
    float r2 = __fdiv_rn(1.f, __fadd_rn(d2, 1e-8f));
    float s  = __fadd_rn(__fadd_rn(r0, r1), r2);
    size_t o = ((size_t)b * N2 + n) * 3;
    idx3[o] = i0; idx3[o + 1] = i1; idx3[o + 2] = i2;
    w3[o]     = __fdiv_rn(r0, s);
    w3[o + 1] = __fdiv_rn(r1, s);
    w3[o + 2] = __fdiv_rn(r2, s);
}

// feats[bn,c] = bf16r( fp32_sum_i(w_i * f1_i) + f2 )   (f1,f2 bf16-valued)
__global__ __launch_bounds__(256) void interp_kernel(
    const float* __restrict__ f1, const int* __restrict__ idx3,
    const float* __restrict__ w3, float* __restrict__ feats)
{
    const int bn = blockIdx.x;
    const int b = bn >> 12;
    const int c = threadIdx.x;
    size_t o = (size_t)bn * 3;
    int i0 = idx3[o], i1 = idx3[o + 1], i2 = idx3[o + 2];
    float w0 = w3[o], w1 = w3[o + 1], w2 = w3[o + 2];
    const float* f1b = f1 + (size_t)b * N1 * 256;
    float itp = w0 * f1b[(size_t)i0 * 256 + c]
              + w1 * f1b[(size_t)i1 * 256 + c]
              + w2 * f1b[(size_t)i2 * 256 + c];
    feats[(size_t)bn * 256 + c] = bf16r(bf16r(itp) + feats[(size_t)bn * 256 + c]);
}

// ---------------------------------------------------------------------------
// KNN top-16 (fp32 coords/distances, stable insertion + stable 4-way merge).
// ---------------------------------------------------------------------------
__global__ __launch_bounds__(256) void knn_kernel(
    const float* __restrict__ xyz2, int* __restrict__ knn_out)
{
    const int b = blockIdx.x >> 6;
    const int q0 = (blockIdx.x & 63) << 6;
    const int tid = threadIdx.x;
    const int ql = tid >> 2, r = tid & 3;
    const int n = q0 + ql;
    __shared__ float sx[N2], sy[N2], sz[N2], sn[N2];
    __shared__ float sd[64][4][16];
    __shared__ int   si[64][4][16];
    for (int i = tid; i < N2; i += 256) {
        const float* p = xyz2 + ((size_t)b * N2 + i) * 3;
        float x = p[0], y = p[1], z = p[2];
        sx[i] = x; sy[i] = y; sz[i] = z;
        sn[i] = norm2_ref(x, y, z);
    }
    __syncthreads();
    const float ax = sx[n], ay = sy[n], az = sz[n];
    const float sa = sn[n];
    float d[16]; int id[16];
#pragma unroll
    for (int s = 0; s < 16; ++s) { d[s] = FLT_MAX; id[s] = 0; }
    const int jbase = r << 10;
    for (int jj = 0; jj < 1024; ++jj) {
        int j = jbase + jj;
        float dist = dist_ref(sa, sn[j], ax, ay, az, sx[j], sy[j], sz[j]);
        if (dist < d[15]) {
#pragma unroll
            for (int s = 15; s >= 0; --s) {
                bool shift = (s > 0) && (dist < d[s - 1]);
                bool place = (dist < d[s]) && !shift;
                float nd = shift ? d[s - 1] : (place ? dist : d[s]);
                int   ni = shift ? id[s - 1] : (place ? j : id[s]);
                d[s] = nd; id[s] = ni;
            }
        }
    }
#pragma unroll
    for (int s = 0; s < 16; ++s) { sd[ql][r][s] = d[s]; si[ql][r][s] = id[s]; }
    __syncthreads();
    if (r == 0) {
        int p0 = 0, p1 = 0, p2 = 0, p3 = 0;
        size_t ob = ((size_t)b * N2 + n) * 16;
        for (int o = 0; o < 16; ++o) {
            float h0 = (p0 < 16) ? sd[ql][0][p0] : FLT_MAX;
            float h1 = (p1 < 16) ? sd[ql][1][p1] : FLT_MAX;
            float h2 = (p2 < 16) ? sd[ql][2][p2] : FLT_MAX;
            float h3 = (p3 < 16) ? sd[ql][3][p3] : FLT_MAX;
            int br = 0; float bd = h0;
            if (h1 < bd) { bd = h1; br = 1; }
            if (h2 < bd) { bd = h2; br = 2; }
            if (h3 < bd) { bd = h3; br = 3; }
            int bi;
            if (br == 0)      { bi = si[ql][0][p0]; ++p0; }
            else if (br == 1) { bi = si[ql][1][p1]; ++p1; }
            else if (br == 2) { bi = si[ql][2][p2]; ++p2; }
            else              { bi = si[ql][3][p3]; ++p3; }
            knn_out[ob + o] = bi;
        }
    }
}

// ---------------------------------------------------------------------------
// Fused attention, bf16-precision values: bf16 operands (weights rounded at
// load; q/k/v/ph/t/h already bf16-valued), fp32 accumulation, bf16-rounded
// materializations. Coordinates raw fp32; rel rounded after subtraction.
// ---------------------------------------------------------------------------
#define GEMM_FMA(ACC, T4, W)                                        \
    {                                                               \
        float4 pa = (T4)[0], pb = (T4)[1], pc4 = (T4)[2], pd = (T4)[3]; \
        ACC[0]  = fmaf(pa.x,  (W), ACC[0]);  ACC[1]  = fmaf(pa.y,  (W), ACC[1]);  \
        ACC[2]  = fmaf(pa.z,  (W), ACC[2]);  ACC[3]  = fmaf(pa.w,  (W), ACC[3]);  \
        ACC[4]  = fmaf(pb.x,  (W), ACC[4]);  ACC[5]  = fmaf(pb.y,  (W), ACC[5]);  \
        ACC[6]  = fmaf(pb.z,  (W), ACC[6]);  ACC[7]  = fmaf(pb.w,  (W), ACC[7]);  \
        ACC[8]  = fmaf(pc4.x, (W), ACC[8]);  ACC[9]  = fmaf(pc4.y, (W), ACC[9]);  \
        ACC[10] = fmaf(pc4.z, (W), ACC[10]); ACC[11] = fmaf(pc4.w, (W), ACC[11]); \
        ACC[12] = fmaf(pd.x,  (W), ACC[12]); ACC[13] = fmaf(pd.y,  (W), ACC[13]); \
        ACC[14] = fmaf(pd.z,  (W), ACC[14]); ACC[15] = fmaf(pd.w,  (W), ACC[15]); \
    }

__global__ __launch_bounds__(256) void attn_kernel(
    const float* __restrict__ xyz2, const float* __restrict__ qg,
    const float* __restrict__ kg, const float* __restrict__ vg,
    const int* __restrict__ knn,
    const float* __restrict__ d1w, const float* __restrict__ d1b,
    const float* __restrict__ d2w, const float* __restrict__ d2b,
    const float* __restrict__ g1w, const float* __restrict__ g1b,
    const float* __restrict__ g2w, const float* __restrict__ g2b,
    float* __restrict__ res)
{
    const int bn = blockIdx.x;
    const int b = bn >> 12;
    const int c = threadIdx.x;
    __shared__ __align__(16) float kf_s[16 * 256];  // [kk][c]
    __shared__ __align__(16) float tA[256 * 16];    // [j][kk]  ph, then h
    __shared__ __align__(16) float tB[256 * 16];    // [j][kk]  t
    __shared__ int   knn_s[16];
    __shared__ float relx[16], rely[16], relz[16];

    if (c < 16) {
        int idx = knn[(size_t)bn * 16 + c];
        knn_s[c] = idx;
        const float* pq = xyz2 + (size_t)bn * 3;
        const float* pk = xyz2 + ((size_t)b * N2 + idx) * 3;
        relx[c] = bf16r(pq[0] - pk[0]);   // raw fp32 sub, bf16 materialize
        rely[c] = bf16r(pq[1] - pk[1]);
        relz[c] = bf16r(pq[2] - pk[2]);
    }
    __syncthreads();

    const size_t basebc = (size_t)b * N2 * 256;
    float vf[16];
#pragma unroll
    for (int kk = 0; kk < 16; ++kk) {
        int row = knn_s[kk];
        kf_s[kk * 256 + c] = kg[basebc + (size_t)row * 256 + c];  // bf16-valued
        vf[kk] = vg[basebc + (size_t)row * 256 + c];
    }
    // ph[kk][c] = relu(bf16r(rel @ d1w)), stored transposed tA[c][kk]
    {
        float w0 = bf16r(d1w[c]), w1 = bf16r(d1w[256 + c]), w2 = bf16r(d1w[512 + c]);
        float bb = d1b[c];
#pragma unroll
        for (int kk = 0; kk < 16; ++kk) {
            float v = fmaf(relx[kk], w0, fmaf(rely[kk], w1, fmaf(relz[kk], w2, bb)));
            tA[c * 16 + kk] = fmaxf(bf16r(v), 0.f);
        }
    }
    __syncthreads();
    // pos[kk][c] = bf16r(ph @ d2w)
    float posr[16];
    {
        float bb = d2b[c];
#pragma unroll
        for (int kk = 0; kk < 16; ++kk) posr[kk] = bb;
        for (int j = 0; j < 256; ++j) {
            float w = bf16r(d2w[(j << 8) + c]);
            const float4* t4 = (const float4*)(tA + (j << 4));
            GEMM_FMA(posr, t4, w)
        }
#pragma unroll
        for (int kk = 0; kk < 16; ++kk) posr[kk] = bf16r(posr[kk]);
    }
    // t = bf16r(bf16r(q - kf) + pos)
    float qv = qg[(size_t)bn * 256 + c];
#pragma unroll
    for (int kk = 0; kk < 16; ++kk)
        tB[c * 16 + kk] = bf16r(bf16r(qv - kf_s[kk * 256 + c]) + posr[kk]);
    __syncthreads();
    // h = relu(bf16r(t @ g1w))
    float hacc[16];
    {
        float bb = g1b[c];
#pragma unroll
        for (int kk = 0; kk < 16; ++kk) hacc[kk] = bb;
        for (int j = 0; j < 256; ++j) {
            float w = bf16r(g1w[(j << 8) + c]);
            const float4* t4 = (const float4*)(tB + (j << 4));
            GEMM_FMA(hacc, t4, w)
        }
    }
#pragma unroll
    for (int kk = 0; kk < 16; ++kk) tA[c * 16 + kk] = fmaxf(bf16r(hacc[kk]), 0.f);
    __syncthreads();
    // a = bf16r(h @ g2w) * 1/16 (exact in bf16)
    float av[16];
    {
        float bb = g2b[c];
#pragma unroll
        for (int kk = 0; kk < 16; ++kk) av[kk] = bb;
        for (int j = 0; j < 256; ++j) {
            float w = bf16r(g2w[(j << 8) + c]);
            const float4* t4 = (const float4*)(tA + (j << 4));
            GEMM_FMA(av, t4, w)
        }
    }
#pragma unroll
    for (int kk = 0; kk < 16; ++kk) av[kk] = bf16r(av[kk]) * 0.0625f;

    // softmax over K: exp materialized bf16, fp32 sum, weights bf16
    float m = av[0];
#pragma unroll
    for (int kk = 1; kk < 16; ++kk) m = fmaxf(m, av[kk]);
    float e[16];
    float s = 0.f;
#pragma unroll
    for (int kk = 0; kk < 16; ++kk) {
        e[kk] = bf16r(expf(av[kk] - m));
        s += e[kk];
    }
#pragma unroll
    for (int kk = 0; kk < 16; ++kk) e[kk] = bf16r(e[kk] / s);

    // res = bf16r( fp32_sum_k( a_k * bf16r(vf + pos) ) )
    float rr = 0.f;
#pragma unroll
    for (int kk = 0; kk < 16; ++kk) {
        float vp = bf16r(vf[kk] + posr[kk]);
        rr = fmaf(e[kk], vp, rr);
    }
    res[(size_t)bn * 256 + c] = bf16r(rr);
}

// ---------------------------------------------------------------------------
extern "C" void kernel_launch(void* const* d_in, const int* in_sizes, int n_in,
                              void* d_out, int out_size, void* d_ws, size_t ws_size,
                              hipStream_t stream)
{
    const float* xyz1     = (const float*)d_in[0];
    const float* points1  = (const float*)d_in[1];
    const float* xyz2     = (const float*)d_in[2];
    const float* points2  = (const float*)d_in[3];
    const float* up_w1    = (const float*)d_in[4];
    const float* up_b1    = (const float*)d_in[5];
    const float* up_w2    = (const float*)d_in[6];
    const float* up_b2    = (const float*)d_in[7];
    const float* fc1_w    = (const float*)d_in[8];
    const float* fc1_b    = (const float*)d_in[9];
    const float* fc2_w    = (const float*)d_in[10];
    const float* fc2_b    = (const float*)d_in[11];
    const float* delta_w1 = (const float*)d_in[12];
    const float* delta_b1 = (const float*)d_in[13];
    const float* delta_w2 = (const float*)d_in[14];
    const float* delta_b2 = (const float*)d_in[15];
    const float* gamma_w1 = (const float*)d_in[16];
    const float* gamma_b1 = (const float*)d_in[17];
    const float* gamma_w2 = (const float*)d_in[18];
    const float* gamma_b2 = (const float*)d_in[19];
    const float* wq       = (const float*)d_in[20];
    const float* wk       = (const float*)d_in[21];
    const float* wv       = (const float*)d_in[22];

    float* ws = (float*)d_ws;
    float* f1    = ws;
    float* feats = f1 + (size_t)BB * N1 * 256;
    float* x     = feats + (size_t)BB * N2 * 256;
    float* qb    = x + (size_t)BB * N2 * 256;
    float* kb    = qb + (size_t)BB * N2 * 256;
    float* vb    = kb + (size_t)BB * N2 * 256;
    int*   idx3  = (int*)(vb + (size_t)BB * N2 * 256);
    float* w3    = (float*)(idx3 + (size_t)BB * N2 * 3);
    int*   knn   = (int*)(w3 + (size_t)BB * N2 * 3);
    float* resb  = x;  // x dead after q/k/v

    float* out = (float*)d_out;
    hipMemcpyAsync(out, xyz2, (size_t)BB * N2 * 3 * sizeof(float),
                   hipMemcpyDeviceToDevice, stream);

    const float BN = (float)(1.0 / sqrt(1.0 + 1e-5));

    // f1 = relu(bf16(points1) @ bf16(up_w1)) [bf16 materialized]
    gemm16<CIN, true, true><<<BB * N1 / 16, 256, 0, stream>>>(points1, up_w1, up_b1, nullptr, BN, f1);
    gemm16<CC, true, true><<<BB * N2 / 16, 256, 0, stream>>>(points2, up_w2, up_b2, nullptr, BN, feats);
    // selection: raw fp32 coords, faithful
    nn3_kernel<<<BB * 16, 256, 0, stream>>>(xyz1, xyz2, idx3, w3);
    interp_kernel<<<BB * N2, 256, 0, stream>>>(f1, idx3, w3, feats);
    // x = bf16r(feats @ bf16(fc1_w))
    gemm16<CC, false, false><<<BB * N2 / 16, 256, 0, stream>>>(feats, fc1_w, fc1_b, nullptr, 1.f, x);
    gemm16<CC, false, false><<<BB * N2 / 16, 256, 0, stream>>>(x, wq, nullptr, nullptr, 1.f, qb);
    gemm16<CC, false, false><<<BB * N2 / 16, 256, 0, stream>>>(x, wk, nullptr, nullptr, 1.f, kb);
    gemm16<CC, false, false><<<BB * N2 / 16, 256, 0, stream>>>(x, wv, nullptr, nullptr, 1.f, vb);
    knn_kernel<<<BB * 64, 256, 0, stream>>>(xyz2, knn);
    attn_kernel<<<BB * N2, 256, 0, stream>>>(xyz2, qb, kb, vb, knn,
                                             delta_w1, delta_b1, delta_w2, delta_b2,
                                             gamma_w1, gamma_b1, gamma_w2, gamma_b2, resb);
    // out1 = bf16r(bf16r(resb @ bf16(fc2_w)) + feats)
    gemm16<CC, false, false><<<BB * N2 / 16, 256, 0, stream>>>(resb, fc2_w, fc2_b, feats, 1.f,
                                                               out + (size_t)BB * N2 * 3);
}

// Round 11
// 2455.956 us; speedup vs baseline: 1.0515x; 1.0515x over previous
//
#include <hip/hip_runtime.h>
#include <hip/hip_bf16.h>
#include <math.h>
#include <float.h>

#define BB   4
#define N1   1024
#define N2   4096
#define CIN  512
#define CC   256
#define DM   256
#define KNNK 16
#define TP   20   // padded LDS row stride (floats); 80B rows stay 16B-aligned

// round-to-nearest-even fp32 -> bf16 -> fp32
__device__ __forceinline__ float bf16r(float x) {
    return __bfloat162float(__float2bfloat16(x));
}

// generic rounding copy: dst = bf16r(src)
__global__ __launch_bounds__(256) void roundcopy(
    const float* __restrict__ src, float* __restrict__ dst, int n)
{
    int i = blockIdx.x * 256 + threadIdx.x;
    int stride = gridDim.x * 256;
    for (; i < n; i += stride) dst[i] = bf16r(src[i]);
}

// ---------------------------------------------------------------------------
// bf16-precision GEMM (identical arithmetic to round 10): X pre-rounded or
// bf16-valued intermediate; W rounded at load; fp32 fma accumulation in the
// same j order; bf16-rounded materializations.
// ---------------------------------------------------------------------------
template<int KD, bool RELU>
__global__ __launch_bounds__(256) void gemm16(
    const float* __restrict__ X, const float* __restrict__ W,
    const float* __restrict__ bias, const float* __restrict__ resid,
    float scale, float* __restrict__ Y)
{
    const int c = threadIdx.x;
    const size_t row0 = (size_t)blockIdx.x * 16;
    const float* Xp = X + row0 * KD;
    float acc[16];
#pragma unroll
    for (int r = 0; r < 16; ++r) acc[r] = 0.f;
    for (int j = 0; j < KD; ++j) {
        float w = bf16r(W[(size_t)j * 256 + c]);
#pragma unroll
        for (int r = 0; r < 16; ++r)
            acc[r] = fmaf(Xp[(size_t)r * KD + j], w, acc[r]);
    }
    float bb = bias ? bias[c] : 0.f;
#pragma unroll
    for (int r = 0; r < 16; ++r) {
        float v = bf16r(acc[r]);
        v = bf16r(v + bb);
        if (scale != 1.f) v = bf16r(v * scale);
        if (RELU) v = fmaxf(v, 0.f);
        if (resid) v = bf16r(v + resid[(row0 + r) * 256 + c]);
        Y[(row0 + r) * 256 + c] = v;
    }
}

// ---- faithful fp32 distance (selection on RAW fp32 coords) ---------------
__device__ __forceinline__ float norm2_ref(float x, float y, float z) {
    return __fadd_rn(__fadd_rn(__fmul_rn(x, x), __fmul_rn(y, y)), __fmul_rn(z, z));
}
__device__ __forceinline__ float dist_ref(float sa, float nb,
                                          float ax, float ay, float az,
                                          float bx, float by, float bz) {
    float dot = __fadd_rn(__fadd_rn(__fmul_rn(ax, bx), __fmul_rn(ay, by)),
                          __fmul_rn(az, bz));
    return __fsub_rn(__fadd_rn(sa, nb), __fmul_rn(2.f, dot));
}

// ---------------------------------------------------------------------------
// 3-NN (unchanged from round 10 — bit-identical selection)
// ---------------------------------------------------------------------------
__global__ __launch_bounds__(256) void nn3_kernel(
    const float* __restrict__ xyz1, const float* __restrict__ xyz2,
    int* __restrict__ idx3, float* __restrict__ w3)
{
    const int b = blockIdx.x >> 4;
    const int n = ((blockIdx.x & 15) << 8) + threadIdx.x;
    __shared__ float sx[N1], sy[N1], sz[N1], snb[N1];
    for (int i = threadIdx.x; i < N1; i += 256) {
        const float* p = xyz1 + ((size_t)b * N1 + i) * 3;
        float x = p[0], y = p[1], z = p[2];
        sx[i] = x; sy[i] = y; sz[i] = z;
        snb[i] = norm2_ref(x, y, z);
    }
    __syncthreads();
    const float* pq = xyz2 + ((size_t)b * N2 + n) * 3;
    const float ax = pq[0], ay = pq[1], az = pq[2];
    const float sa = norm2_ref(ax, ay, az);
    float d0 = FLT_MAX, d1 = FLT_MAX, d2 = FLT_MAX;
    int i0 = 0, i1 = 0, i2 = 0;
    for (int j = 0; j < N1; ++j) {
        float dist = dist_ref(sa, snb[j], ax, ay, az, sx[j], sy[j], sz[j]);
        if (dist < d2) {
            if (dist < d1) {
                d2 = d1; i2 = i1;
                if (dist < d0) { d1 = d0; i1 = i0; d0 = dist; i0 = j; }
                else           { d1 = dist; i1 = j; }
            } else { d2 = dist; i2 = j; }
        }
    }
    float r0 = __fdiv_rn(1.f, __fadd_rn(d0, 1e-8f));
    float r1 = __fdiv_rn(1.f, __fadd_rn(d1, 1e-8f));
    float r2 = __fdiv_rn(1.f, __fadd_rn(d2, 1e-8f));
    float s  = __fadd_rn(__fadd_rn(r0, r1), r2);
    size_t o = ((size_t)b * N2 + n) * 3;
    idx3[o] = i0; idx3[o + 1] = i1; idx3[o + 2] = i2;
    w3[o]     = __fdiv_rn(r0, s);
    w3[o + 1] = __fdiv_rn(r1, s);
    w3[o + 2] = __fdiv_rn(r2, s);
}

// feats[bn,c] = bf16r( bf16r(fp32_sum w_i*f1_i) + f2 )  (unchanged)
__global__ __launch_bounds__(256) void interp_kernel(
    const float* __restrict__ f1, const int* __restrict__ idx3,
    const float* __restrict__ w3, float* __restrict__ feats)
{
    const int bn = blockIdx.x;
    const int b = bn >> 12;
    const int c = threadIdx.x;
    size_t o = (size_t)bn * 3;
    int i0 = idx3[o], i1 = idx3[o + 1], i2 = idx3[o + 2];
    float w0 = w3[o], w1 = w3[o + 1], w2 = w3[o + 2];
    const float* f1b = f1 + (size_t)b * N1 * 256;
    float itp = w0 * f1b[(size_t)i0 * 256 + c]
              + w1 * f1b[(size_t)i1 * 256 + c]
              + w2 * f1b[(size_t)i2 * 256 + c];
    feats[(size_t)bn * 256 + c] = bf16r(bf16r(itp) + feats[(size_t)bn * 256 + c]);
}

// ---------------------------------------------------------------------------
// KNN top-16 (unchanged from round 10 — bit-identical selection)
// ---------------------------------------------------------------------------
__global__ __launch_bounds__(256) void knn_kernel(
    const float* __restrict__ xyz2, int* __restrict__ knn_out)
{
    const int b = blockIdx.x >> 6;
    const int q0 = (blockIdx.x & 63) << 6;
    const int tid = threadIdx.x;
    const int ql = tid >> 2, r = tid & 3;
    const int n = q0 + ql;
    __shared__ float sx[N2], sy[N2], sz[N2], sn[N2];
    __shared__ float sd[64][4][16];
    __shared__ int   si[64][4][16];
    for (int i = tid; i < N2; i += 256) {
        const float* p = xyz2 + ((size_t)b * N2 + i) * 3;
        float x = p[0], y = p[1], z = p[2];
        sx[i] = x; sy[i] = y; sz[i] = z;
        sn[i] = norm2_ref(x, y, z);
    }
    __syncthreads();
    const float ax = sx[n], ay = sy[n], az = sz[n];
    const float sa = sn[n];
    float d[16]; int id[16];
#pragma unroll
    for (int s = 0; s < 16; ++s) { d[s] = FLT_MAX; id[s] = 0; }
    const int jbase = r << 10;
    for (int jj = 0; jj < 1024; ++jj) {
        int j = jbase + jj;
        float dist = dist_ref(sa, sn[j], ax, ay, az, sx[j], sy[j], sz[j]);
        if (dist < d[15]) {
#pragma unroll
            for (int s = 15; s >= 0; --s) {
                bool shift = (s > 0) && (dist < d[s - 1]);
                bool place = (dist < d[s]) && !shift;
                float nd = shift ? d[s - 1] : (place ? dist : d[s]);
                int   ni = shift ? id[s - 1] : (place ? j : id[s]);
                d[s] = nd; id[s] = ni;
            }
        }
    }
#pragma unroll
    for (int s = 0; s < 16; ++s) { sd[ql][r][s] = d[s]; si[ql][r][s] = id[s]; }
    __syncthreads();
    if (r == 0) {
        int p0 = 0, p1 = 0, p2 = 0, p3 = 0;
        size_t ob = ((size_t)b * N2 + n) * 16;
        for (int o = 0; o < 16; ++o) {
            float h0 = (p0 < 16) ? sd[ql][0][p0] : FLT_MAX;
            float h1 = (p1 < 16) ? sd[ql][1][p1] : FLT_MAX;
            float h2 = (p2 < 16) ? sd[ql][2][p2] : FLT_MAX;
            float h3 = (p3 < 16) ? sd[ql][3][p3] : FLT_MAX;
            int br = 0; float bd = h0;
            if (h1 < bd) { bd = h1; br = 1; }
            if (h2 < bd) { bd = h2; br = 2; }
            if (h3 < bd) { bd = h3; br = 3; }
            int bi;
            if (br == 0)      { bi = si[ql][0][p0]; ++p0; }
            else if (br == 1) { bi = si[ql][1][p1]; ++p1; }
            else if (br == 2) { bi = si[ql][2][p2]; ++p2; }
            else              { bi = si[ql][3][p3]; ++p3; }
            knn_out[ob + o] = bi;
        }
    }
}

// ---------------------------------------------------------------------------
// Fused attention, restructured for occupancy/conflicts; ARITHMETIC IDENTICAL
// to round 10 (same fmaf chains, same rounding points). Single padded LDS
// tile T[256][TP] reused ph -> t -> h; kf in registers; float4 stores.
// ---------------------------------------------------------------------------
#define GEMM_FMA(ACC, T4, W)                                        \
    {                                                               \
        float4 pa = (T4)[0], pb = (T4)[1], pc4 = (T4)[2], pd = (T4)[3]; \
        ACC[0]  = fmaf(pa.x,  (W), ACC[0]);  ACC[1]  = fmaf(pa.y,  (W), ACC[1]);  \
        ACC[2]  = fmaf(pa.z,  (W), ACC[2]);  ACC[3]  = fmaf(pa.w,  (W), ACC[3]);  \
        ACC[4]  = fmaf(pb.x,  (W), ACC[4]);  ACC[5]  = fmaf(pb.y,  (W), ACC[5]);  \
        ACC[6]  = fmaf(pb.z,  (W), ACC[6]);  ACC[7]  = fmaf(pb.w,  (W), ACC[7]);  \
        ACC[8]  = fmaf(pc4.x, (W), ACC[8]);  ACC[9]  = fmaf(pc4.y, (W), ACC[9]);  \
        ACC[10] = fmaf(pc4.z, (W), ACC[10]); ACC[11] = fmaf(pc4.w, (W), ACC[11]); \
        ACC[12] = fmaf(pd.x,  (W), ACC[12]); ACC[13] = fmaf(pd.y,  (W), ACC[13]); \
        ACC[14] = fmaf(pd.z,  (W), ACC[14]); ACC[15] = fmaf(pd.w,  (W), ACC[15]); \
    }

#define STORE16(V)                                                   \
    {                                                                \
        float4* tp = (float4*)(T + c * TP);                          \
        tp[0] = make_float4(V[0],  V[1],  V[2],  V[3]);              \
        tp[1] = make_float4(V[4],  V[5],  V[6],  V[7]);              \
        tp[2] = make_float4(V[8],  V[9],  V[10], V[11]);             \
        tp[3] = make_float4(V[12], V[13], V[14], V[15]);             \
    }

__global__ __launch_bounds__(256) void attn_kernel(
    const float* __restrict__ xyz2, const float* __restrict__ qg,
    const float* __restrict__ kg, const float* __restrict__ vg,
    const int* __restrict__ knn,
    const float* __restrict__ d1w, const float* __restrict__ d1b,
    const float* __restrict__ d2w, const float* __restrict__ d2b,
    const float* __restrict__ g1w, const float* __restrict__ g1b,
    const float* __restrict__ g2w, const float* __restrict__ g2b,
    float* __restrict__ res)
{
    const int bn = blockIdx.x;
    const int b = bn >> 12;
    const int c = threadIdx.x;
    __shared__ __align__(16) float T[256 * TP];   // 20 KiB
    __shared__ int   knn_s[16];
    __shared__ float relx[16], rely[16], relz[16];

    if (c < 16) {
        int idx = knn[(size_t)bn * 16 + c];
        knn_s[c] = idx;
        const float* pq = xyz2 + (size_t)bn * 3;
        const float* pk = xyz2 + ((size_t)b * N2 + idx) * 3;
        relx[c] = bf16r(pq[0] - pk[0]);
        rely[c] = bf16r(pq[1] - pk[1]);
        relz[c] = bf16r(pq[2] - pk[2]);
    }
    __syncthreads();

    const size_t basebc = (size_t)b * N2 * 256;
    float kf[16], vf[16];
#pragma unroll
    for (int kk = 0; kk < 16; ++kk) {
        int row = knn_s[kk];
        kf[kk] = kg[basebc + (size_t)row * 256 + c];
        vf[kk] = vg[basebc + (size_t)row * 256 + c];
    }
    float qv = qg[(size_t)bn * 256 + c];

    // ph[kk][c] = relu(bf16r(rel @ d1w))  -> T (transposed [c][kk])
    float v16[16];
    {
        float w0 = bf16r(d1w[c]), w1 = bf16r(d1w[256 + c]), w2 = bf16r(d1w[512 + c]);
        float bb = d1b[c];
#pragma unroll
        for (int kk = 0; kk < 16; ++kk) {
            float v = fmaf(relx[kk], w0, fmaf(rely[kk], w1, fmaf(relz[kk], w2, bb)));
            v16[kk] = fmaxf(bf16r(v), 0.f);
        }
    }
    STORE16(v16)
    __syncthreads();

    // pos = bf16r(ph @ d2w + d2b)
    float posr[16];
    {
        float bb = d2b[c];
#pragma unroll
        for (int kk = 0; kk < 16; ++kk) posr[kk] = bb;
        for (int j = 0; j < 256; ++j) {
            float w = bf16r(d2w[(j << 8) + c]);
            const float4* t4 = (const float4*)(T + j * TP);
            GEMM_FMA(posr, t4, w)
        }
#pragma unroll
        for (int kk = 0; kk < 16; ++kk) posr[kk] = bf16r(posr[kk]);
    }
    __syncthreads();   // all ph reads done before overwrite

    // t = bf16r(bf16r(q - kf) + pos)  -> T
#pragma unroll
    for (int kk = 0; kk < 16; ++kk)
        v16[kk] = bf16r(bf16r(qv - kf[kk]) + posr[kk]);
    STORE16(v16)
    __syncthreads();

    // h = relu(bf16r(t @ g1w + g1b))
    float hacc[16];
    {
        float bb = g1b[c];
#pragma unroll
        for (int kk = 0; kk < 16; ++kk) hacc[kk] = bb;
        for (int j = 0; j < 256; ++j) {
            float w = bf16r(g1w[(j << 8) + c]);
            const float4* t4 = (const float4*)(T + j * TP);
            GEMM_FMA(hacc, t4, w)
        }
    }
#pragma unroll
    for (int kk = 0; kk < 16; ++kk) v16[kk] = fmaxf(bf16r(hacc[kk]), 0.f);
    __syncthreads();   // all t reads done before overwrite
    STORE16(v16)
    __syncthreads();

    // a = bf16r(h @ g2w + g2b) * 1/16
    float av[16];
    {
        float bb = g2b[c];
#pragma unroll
        for (int kk = 0; kk < 16; ++kk) av[kk] = bb;
        for (int j = 0; j < 256; ++j) {
            float w = bf16r(g2w[(j << 8) + c]);
            const float4* t4 = (const float4*)(T + j * TP);
            GEMM_FMA(av, t4, w)
        }
    }
#pragma unroll
    for (int kk = 0; kk < 16; ++kk) av[kk] = bf16r(av[kk]) * 0.0625f;

    // softmax over K: exp bf16, fp32 sum, weights bf16  (identical to r10)
    float m = av[0];
#pragma unroll
    for (int kk = 1; kk < 16; ++kk) m = fmaxf(m, av[kk]);
    float e[16];
    float s = 0.f;
#pragma unroll
    for (int kk = 0; kk < 16; ++kk) {
        e[kk] = bf16r(expf(av[kk] - m));
        s += e[kk];
    }
#pragma unroll
    for (int kk = 0; kk < 16; ++kk) e[kk] = bf16r(e[kk] / s);

    float rr = 0.f;
#pragma unroll
    for (int kk = 0; kk < 16; ++kk) {
        float vp = bf16r(vf[kk] + posr[kk]);
        rr = fmaf(e[kk], vp, rr);
    }
    res[(size_t)bn * 256 + c] = bf16r(rr);
}

// ---------------------------------------------------------------------------
extern "C" void kernel_launch(void* const* d_in, const int* in_sizes, int n_in,
                              void* d_out, int out_size, void* d_ws, size_t ws_size,
                              hipStream_t stream)
{
    const float* xyz1     = (const float*)d_in[0];
    const float* points1  = (const float*)d_in[1];
    const float* xyz2     = (const float*)d_in[2];
    const float* points2  = (const float*)d_in[3];
    const float* up_w1    = (const float*)d_in[4];
    const float* up_b1    = (const float*)d_in[5];
    const float* up_w2    = (const float*)d_in[6];
    const float* up_b2    = (const float*)d_in[7];
    const float* fc1_w    = (const float*)d_in[8];
    const float* fc1_b    = (const float*)d_in[9];
    const float* fc2_w    = (const float*)d_in[10];
    const float* fc2_b    = (const float*)d_in[11];
    const float* delta_w1 = (const float*)d_in[12];
    const float* delta_b1 = (const float*)d_in[13];
    const float* delta_w2 = (const float*)d_in[14];
    const float* delta_b2 = (const float*)d_in[15];
    const float* gamma_w1 = (const float*)d_in[16];
    const float* gamma_b1 = (const float*)d_in[17];
    const float* gamma_w2 = (const float*)d_in[18];
    const float* gamma_b2 = (const float*)d_in[19];
    const float* wq       = (const float*)d_in[20];
    const float* wk       = (const float*)d_in[21];
    const float* wv       = (const float*)d_in[22];

    float* ws = (float*)d_ws;
    float* f1    = ws;
    float* feats = f1 + (size_t)BB * N1 * 256;
    float* x     = feats + (size_t)BB * N2 * 256;
    float* qb    = x + (size_t)BB * N2 * 256;
    float* kb    = qb + (size_t)BB * N2 * 256;
    float* vb    = kb + (size_t)BB * N2 * 256;
    int*   idx3  = (int*)(vb + (size_t)BB * N2 * 256);
    float* w3    = (float*)(idx3 + (size_t)BB * N2 * 3);
    int*   knn   = (int*)(w3 + (size_t)BB * N2 * 3);
    float* resb  = x;   // x dead after q/k/v
    float* prbuf = qb;  // qb region reused as pre-rounded points scratch

    float* out = (float*)d_out;
    hipMemcpyAsync(out, xyz2, (size_t)BB * N2 * 3 * sizeof(float),
                   hipMemcpyDeviceToDevice, stream);

    const float BN = (float)(1.0 / sqrt(1.0 + 1e-5));

    // pre-round points2 -> prbuf; f2 = relu(bf16(points2) @ bf16(up_w2) * bn)
    roundcopy<<<2048, 256, 0, stream>>>(points2, prbuf, BB * N2 * CC);
    gemm16<CC, true><<<BB * N2 / 16, 256, 0, stream>>>(prbuf, up_w2, up_b2, nullptr, BN, feats);
    // pre-round points1 -> prbuf; f1 = relu(bf16(points1) @ bf16(up_w1) * bn)
    roundcopy<<<2048, 256, 0, stream>>>(points1, prbuf, BB * N1 * CIN);
    gemm16<CIN, true><<<BB * N1 / 16, 256, 0, stream>>>(prbuf, up_w1, up_b1, nullptr, BN, f1);
    // selection on raw fp32 coords (bit-identical to round 10)
    nn3_kernel<<<BB * 16, 256, 0, stream>>>(xyz1, xyz2, idx3, w3);
    interp_kernel<<<BB * N2, 256, 0, stream>>>(f1, idx3, w3, feats);
    // x = bf16r(feats @ bf16(fc1_w))
    gemm16<CC, false><<<BB * N2 / 16, 256, 0, stream>>>(feats, fc1_w, fc1_b, nullptr, 1.f, x);
    // q/k/v (qb overwrites prbuf — points scratch dead)
    gemm16<CC, false><<<BB * N2 / 16, 256, 0, stream>>>(x, wq, nullptr, nullptr, 1.f, qb);
    gemm16<CC, false><<<BB * N2 / 16, 256, 0, stream>>>(x, wk, nullptr, nullptr, 1.f, kb);
    gemm16<CC, false><<<BB * N2 / 16, 256, 0, stream>>>(x, wv, nullptr, nullptr, 1.f, vb);
    knn_kernel<<<BB * 64, 256, 0, stream>>>(xyz2, knn);
    attn_kernel<<<BB * N2, 256, 0, stream>>>(xyz2, qb, kb, vb, knn,
                                             delta_w1, delta_b1, delta_w2, delta_b2,
                                             gamma_w1, gamma_b1, gamma_w2, gamma_b2, resb);
    // out1 = bf16r(bf16r(resb @ bf16(fc2_w)) + feats)
    gemm16<CC, false><<<BB * N2 / 16, 256, 0, stream>>>(resb, fc2_w, fc2_b, feats, 1.f,
                                                        out + (size_t)BB * N2 * 3);
}

// Round 12
// 1158.840 us; speedup vs baseline: 2.2285x; 2.1193x over previous
//
#include <hip/hip_runtime.h>
#include <hip/hip_bf16.h>
#include <math.h>
#include <float.h>

#define BB   4
#define N1   1024
#define N2   4096
#define CIN  512
#define CC   256
#define DM   256
#define KNNK 16

typedef __attribute__((ext_vector_type(8))) short bf16x8;
typedef __attribute__((ext_vector_type(4))) float f32x4;

// round-to-nearest-even fp32 -> bf16 -> fp32
__device__ __forceinline__ float bf16r(float x) {
    return __bfloat162float(__float2bfloat16(x));
}
__device__ __forceinline__ unsigned short f2bu(float x) {
    __hip_bfloat16 h = __float2bfloat16(x);
    return *reinterpret_cast<unsigned short*>(&h);
}
__device__ __forceinline__ float bu2f(unsigned short u) {
    __hip_bfloat16 h = *reinterpret_cast<__hip_bfloat16*>(&u);
    return __bfloat162float(h);
}

// generic rounding copy: dst = bf16r(src)
__global__ __launch_bounds__(256) void roundcopy(
    const float* __restrict__ src, float* __restrict__ dst, int n)
{
    int i = blockIdx.x * 256 + threadIdx.x;
    int stride = gridDim.x * 256;
    for (; i < n; i += stride) dst[i] = bf16r(src[i]);
}

// Swizzle W[256][256] fp32 row-major -> bf16 MFMA-B-frag layout:
// B[((kb*16+tile)*64+l)*8 + i] = bf16(W[kb*32+(l>>4)*8+i][tile*16+(l&15)])
__global__ __launch_bounds__(256) void swizzleW(
    const float* __restrict__ W, unsigned short* __restrict__ B)
{
    int idx = blockIdx.x * 256 + threadIdx.x;   // 0..8191
    if (idx >= 8192) return;
    int l = idx & 63;
    int tile = (idx >> 6) & 15;
    int kb = idx >> 10;
    int col = tile * 16 + (l & 15);
    int k0 = kb * 32 + ((l >> 4) << 3);
#pragma unroll
    for (int i = 0; i < 8; ++i)
        B[(size_t)idx * 8 + i] = f2bu(W[(size_t)(k0 + i) * 256 + col]);
}

// ---------------------------------------------------------------------------
// bf16-precision GEMM (unchanged from round 11 — bit-identical)
// ---------------------------------------------------------------------------
template<int KD, bool RELU>
__global__ __launch_bounds__(256) void gemm16(
    const float* __restrict__ X, const float* __restrict__ W,
    const float* __restrict__ bias, const float* __restrict__ resid,
    float scale, float* __restrict__ Y)
{
    const int c = threadIdx.x;
    const size_t row0 = (size_t)blockIdx.x * 16;
    const float* Xp = X + row0 * KD;
    float acc[16];
#pragma unroll
    for (int r = 0; r < 16; ++r) acc[r] = 0.f;
    for (int j = 0; j < KD; ++j) {
        float w = bf16r(W[(size_t)j * 256 + c]);
#pragma unroll
        for (int r = 0; r < 16; ++r)
            acc[r] = fmaf(Xp[(size_t)r * KD + j], w, acc[r]);
    }
    float bb = bias ? bias[c] : 0.f;
#pragma unroll
    for (int r = 0; r < 16; ++r) {
        float v = bf16r(acc[r]);
        v = bf16r(v + bb);
        if (scale != 1.f) v = bf16r(v * scale);
        if (RELU) v = fmaxf(v, 0.f);
        if (resid) v = bf16r(v + resid[(row0 + r) * 256 + c]);
        Y[(row0 + r) * 256 + c] = v;
    }
}

// ---- faithful fp32 distance (selection on RAW fp32 coords) ---------------
__device__ __forceinline__ float norm2_ref(float x, float y, float z) {
    return __fadd_rn(__fadd_rn(__fmul_rn(x, x), __fmul_rn(y, y)), __fmul_rn(z, z));
}
__device__ __forceinline__ float dist_ref(float sa, float nb,
                                          float ax, float ay, float az,
                                          float bx, float by, float bz) {
    float dot = __fadd_rn(__fadd_rn(__fmul_rn(ax, bx), __fmul_rn(ay, by)),
                          __fmul_rn(az, bz));
    return __fsub_rn(__fadd_rn(sa, nb), __fmul_rn(2.f, dot));
}

// ---------------------------------------------------------------------------
// 3-NN (unchanged — bit-identical selection)
// ---------------------------------------------------------------------------
__global__ __launch_bounds__(256) void nn3_kernel(
    const float* __restrict__ xyz1, const float* __restrict__ xyz2,
    int* __restrict__ idx3, float* __restrict__ w3)
{
    const int b = blockIdx.x >> 4;
    const int n = ((blockIdx.x & 15) << 8) + threadIdx.x;
    __shared__ float sx[N1], sy[N1], sz[N1], snb[N1];
    for (int i = threadIdx.x; i < N1; i += 256) {
        const float* p = xyz1 + ((size_t)b * N1 + i) * 3;
        float x = p[0], y = p[1], z = p[2];
        sx[i] = x; sy[i] = y; sz[i] = z;
        snb[i] = norm2_ref(x, y, z);
    }
    __syncthreads();
    const float* pq = xyz2 + ((size_t)b * N2 + n) * 3;
    const float ax = pq[0], ay = pq[1], az = pq[2];
    const float sa = norm2_ref(ax, ay, az);
    float d0 = FLT_MAX, d1 = FLT_MAX, d2 = FLT_MAX;
    int i0 = 0, i1 = 0, i2 = 0;
    for (int j = 0; j < N1; ++j) {
        float dist = dist_ref(sa, snb[j], ax, ay, az, sx[j], sy[j], sz[j]);
        if (dist < d2) {
            if (dist < d1) {
                d2 = d1; i2 = i1;
                if (dist < d0) { d1 = d0; i1 = i0; d0 = dist; i0 = j; }
                else           { d1 = dist; i1 = j; }
            } else { d2 = dist; i2 = j; }
        }
    }
    float r0 = __fdiv_rn(1.f, __fadd_rn(d0, 1e-8f));
    float r1 = __fdiv_rn(1.f, __fadd_rn(d1, 1e-8f));
    float r2 = __fdiv_rn(1.f, __fadd_rn(d2, 1e-8f));
    float s  = __fadd_rn(__fadd_rn(r0, r1), r2);
    size_t o = ((size_t)b * N2 + n) * 3;
    idx3[o] = i0; idx3[o + 1] = i1; idx3[o + 2] = i2;
    w3[o]     = __fdiv_rn(r0, s);
    w3[o + 1] = __fdiv_rn(r1, s);
    w3[o + 2] = __fdiv_rn(r2, s);
}

// feats[bn,c] = bf16r( bf16r(fp32_sum w_i*f1_i) + f2 )  (unchanged)
__global__ __launch_bounds__(256) void interp_kernel(
    const float* __restrict__ f1, const int* __restrict__ idx3,
    const float* __restrict__ w3, float* __restrict__ feats)
{
    const int bn = blockIdx.x;
    const int b = bn >> 12;
    const int c = threadIdx.x;
    size_t o = (size_t)bn * 3;
    int i0 = idx3[o], i1 = idx3[o + 1], i2 = idx3[o + 2];
    float w0 = w3[o], w1 = w3[o + 1], w2 = w3[o + 2];
    const float* f1b = f1 + (size_t)b * N1 * 256;
    float itp = w0 * f1b[(size_t)i0 * 256 + c]
              + w1 * f1b[(size_t)i1 * 256 + c]
              + w2 * f1b[(size_t)i2 * 256 + c];
    feats[(size_t)bn * 256 + c] = bf16r(bf16r(itp) + feats[(size_t)bn * 256 + c]);
}

// ---------------------------------------------------------------------------
// KNN top-16 (unchanged — bit-identical selection)
// ---------------------------------------------------------------------------
__global__ __launch_bounds__(256) void knn_kernel(
    const float* __restrict__ xyz2, int* __restrict__ knn_out)
{
    const int b = blockIdx.x >> 6;
    const int q0 = (blockIdx.x & 63) << 6;
    const int tid = threadIdx.x;
    const int ql = tid >> 2, r = tid & 3;
    const int n = q0 + ql;
    __shared__ float sx[N2], sy[N2], sz[N2], sn[N2];
    __shared__ float sd[64][4][16];
    __shared__ int   si[64][4][16];
    for (int i = tid; i < N2; i += 256) {
        const float* p = xyz2 + ((size_t)b * N2 + i) * 3;
        float x = p[0], y = p[1], z = p[2];
        sx[i] = x; sy[i] = y; sz[i] = z;
        sn[i] = norm2_ref(x, y, z);
    }
    __syncthreads();
    const float ax = sx[n], ay = sy[n], az = sz[n];
    const float sa = sn[n];
    float d[16]; int id[16];
#pragma unroll
    for (int s = 0; s < 16; ++s) { d[s] = FLT_MAX; id[s] = 0; }
    const int jbase = r << 10;
    for (int jj = 0; jj < 1024; ++jj) {
        int j = jbase + jj;
        float dist = dist_ref(sa, sn[j], ax, ay, az, sx[j], sy[j], sz[j]);
        if (dist < d[15]) {
#pragma unroll
            for (int s = 15; s >= 0; --s) {
                bool shift = (s > 0) && (dist < d[s - 1]);
                bool place = (dist < d[s]) && !shift;
                float nd = shift ? d[s - 1] : (place ? dist : d[s]);
                int   ni = shift ? id[s - 1] : (place ? j : id[s]);
                d[s] = nd; id[s] = ni;
            }
        }
    }
#pragma unroll
    for (int s = 0; s < 16; ++s) { sd[ql][r][s] = d[s]; si[ql][r][s] = id[s]; }
    __syncthreads();
    if (r == 0) {
        int p0 = 0, p1 = 0, p2 = 0, p3 = 0;
        size_t ob = ((size_t)b * N2 + n) * 16;
        for (int o = 0; o < 16; ++o) {
            float h0 = (p0 < 16) ? sd[ql][0][p0] : FLT_MAX;
            float h1 = (p1 < 16) ? sd[ql][1][p1] : FLT_MAX;
            float h2 = (p2 < 16) ? sd[ql][2][p2] : FLT_MAX;
            float h3 = (p3 < 16) ? sd[ql][3][p3] : FLT_MAX;
            int br = 0; float bd = h0;
            if (h1 < bd) { bd = h1; br = 1; }
            if (h2 < bd) { bd = h2; br = 2; }
            if (h3 < bd) { bd = h3; br = 3; }
            int bi;
            if (br == 0)      { bi = si[ql][0][p0]; ++p0; }
            else if (br == 1) { bi = si[ql][1][p1]; ++p1; }
            else if (br == 2) { bi = si[ql][2][p2]; ++p2; }
            else              { bi = si[ql][3][p3]; ++p3; }
            knn_out[ob + o] = bi;
        }
    }
}

// ---------------------------------------------------------------------------
// MFMA attention. One block (256 thr = 4 waves) per point. The 3 GEMM chains
// (pos/h/a) run on mfma_f32_16x16x32_bf16: A (ph/t/h) staged in LDS bf16
// [16][264]; B = pre-swizzled bf16 weights from global. Same rounding points
// as round 11; biases are zeros so only intra-sum order differs.
// ---------------------------------------------------------------------------
__global__ __launch_bounds__(256) void attn_mfma(
    const float* __restrict__ xyz2, const float* __restrict__ qg,
    const float* __restrict__ kg, const float* __restrict__ vg,
    const int* __restrict__ knn,
    const float* __restrict__ d1w, const float* __restrict__ d1b,
    const float* __restrict__ d2b, const float* __restrict__ g1b,
    const float* __restrict__ g2b,
    const unsigned short* __restrict__ Bd2,
    const unsigned short* __restrict__ Bg1,
    const unsigned short* __restrict__ Bg2,
    float* __restrict__ res)
{
    const int bn = blockIdx.x;
    const int b = bn >> 12;
    const int c = threadIdx.x;
    const int l = c & 63, wv_ = c >> 6;
    const int lr = l & 15, lg = l >> 4;

    __shared__ __align__(16) unsigned short phb[16][264];   // A: ph -> t -> h
    __shared__ __align__(16) unsigned short posb[16][264];  // pos, then a
    __shared__ int   knn_s[16];
    __shared__ float relx[16], rely[16], relz[16];

    if (c < 16) {
        int idx = knn[(size_t)bn * 16 + c];
        knn_s[c] = idx;
        const float* pq = xyz2 + (size_t)bn * 3;
        const float* pk = xyz2 + ((size_t)b * N2 + idx) * 3;
        relx[c] = bf16r(pq[0] - pk[0]);
        rely[c] = bf16r(pq[1] - pk[1]);
        relz[c] = bf16r(pq[2] - pk[2]);
    }
    __syncthreads();

    const size_t basebc = (size_t)b * N2 * 256;
    float kf[16], vf[16];
#pragma unroll
    for (int kk = 0; kk < 16; ++kk) {
        int row = knn_s[kk];
        kf[kk] = kg[basebc + (size_t)row * 256 + c];
        vf[kk] = vg[basebc + (size_t)row * 256 + c];
    }
    float qv = qg[(size_t)bn * 256 + c];

    // ph[kk][c] = relu(bf16r(rel @ d1w + d1b))  (bit-identical chain) -> LDS bf16
    {
        float w0 = bf16r(d1w[c]), w1 = bf16r(d1w[256 + c]), w2 = bf16r(d1w[512 + c]);
        float bb = d1b[c];
#pragma unroll
        for (int kk = 0; kk < 16; ++kk) {
            float v = fmaf(relx[kk], w0, fmaf(rely[kk], w1, fmaf(relz[kk], w2, bb)));
            phb[kk][c] = f2bu(fmaxf(bf16r(v), 0.f));
        }
    }
    __syncthreads();

    // ---- pos chain: pos = bf16r(ph @ d2w + d2b) ----
    f32x4 a0 = {0.f,0.f,0.f,0.f}, a1 = a0, a2 = a0, a3 = a0;
    for (int kb = 0; kb < 8; ++kb) {
        bf16x8 af = *(const bf16x8*)&phb[lr][kb * 32 + lg * 8];
        bf16x8 b0 = *(const bf16x8*)&Bd2[((size_t)(kb * 16 + wv_ * 4 + 0) * 64 + l) * 8];
        bf16x8 b1 = *(const bf16x8*)&Bd2[((size_t)(kb * 16 + wv_ * 4 + 1) * 64 + l) * 8];
        bf16x8 b2 = *(const bf16x8*)&Bd2[((size_t)(kb * 16 + wv_ * 4 + 2) * 64 + l) * 8];
        bf16x8 b3 = *(const bf16x8*)&Bd2[((size_t)(kb * 16 + wv_ * 4 + 3) * 64 + l) * 8];
        a0 = __builtin_amdgcn_mfma_f32_16x16x32_bf16(af, b0, a0, 0, 0, 0);
        a1 = __builtin_amdgcn_mfma_f32_16x16x32_bf16(af, b1, a1, 0, 0, 0);
        a2 = __builtin_amdgcn_mfma_f32_16x16x32_bf16(af, b2, a2, 0, 0, 0);
        a3 = __builtin_amdgcn_mfma_f32_16x16x32_bf16(af, b3, a3, 0, 0, 0);
    }
#pragma unroll
    for (int t = 0; t < 4; ++t) {
        const f32x4 av4 = (t == 0) ? a0 : (t == 1) ? a1 : (t == 2) ? a2 : a3;
        int col = (wv_ * 4 + t) * 16 + lr;
        float bb = d2b[col];
#pragma unroll
        for (int r = 0; r < 4; ++r)
            posb[lg * 4 + r][col] = f2bu(bf16r(av4[r] + bb));
    }
    __syncthreads();

    // t = bf16r(bf16r(q - kf) + pos) -> LDS bf16 (A for h-chain)
    float posr[16];
#pragma unroll
    for (int kk = 0; kk < 16; ++kk) posr[kk] = bu2f(posb[kk][c]);
#pragma unroll
    for (int kk = 0; kk < 16; ++kk)
        phb[kk][c] = f2bu(bf16r(bf16r(qv - kf[kk]) + posr[kk]));
    __syncthreads();

    // ---- h chain: h = relu(bf16r(t @ g1w + g1b)) ----
    a0 = (f32x4){0.f,0.f,0.f,0.f}; a1 = a0; a2 = a0; a3 = a0;
    for (int kb = 0; kb < 8; ++kb) {
        bf16x8 af = *(const bf16x8*)&phb[lr][kb * 32 + lg * 8];
        bf16x8 b0 = *(const bf16x8*)&Bg1[((size_t)(kb * 16 + wv_ * 4 + 0) * 64 + l) * 8];
        bf16x8 b1 = *(const bf16x8*)&Bg1[((size_t)(kb * 16 + wv_ * 4 + 1) * 64 + l) * 8];
        bf16x8 b2 = *(const bf16x8*)&Bg1[((size_t)(kb * 16 + wv_ * 4 + 2) * 64 + l) * 8];
        bf16x8 b3 = *(const bf16x8*)&Bg1[((size_t)(kb * 16 + wv_ * 4 + 3) * 64 + l) * 8];
        a0 = __builtin_amdgcn_mfma_f32_16x16x32_bf16(af, b0, a0, 0, 0, 0);
        a1 = __builtin_amdgcn_mfma_f32_16x16x32_bf16(af, b1, a1, 0, 0, 0);
        a2 = __builtin_amdgcn_mfma_f32_16x16x32_bf16(af, b2, a2, 0, 0, 0);
        a3 = __builtin_amdgcn_mfma_f32_16x16x32_bf16(af, b3, a3, 0, 0, 0);
    }
    __syncthreads();   // all t reads complete before phb overwrite
#pragma unroll
    for (int t = 0; t < 4; ++t) {
        const f32x4 av4 = (t == 0) ? a0 : (t == 1) ? a1 : (t == 2) ? a2 : a3;
        int col = (wv_ * 4 + t) * 16 + lr;
        float bb = g1b[col];
#pragma unroll
        for (int r = 0; r < 4; ++r)
            phb[lg * 4 + r][col] = f2bu(fmaxf(bf16r(av4[r] + bb), 0.f));
    }
    __syncthreads();

    // ---- a chain: a = bf16r(h @ g2w + g2b) ----
    a0 = (f32x4){0.f,0.f,0.f,0.f}; a1 = a0; a2 = a0; a3 = a0;
    for (int kb = 0; kb < 8; ++kb) {
        bf16x8 af = *(const bf16x8*)&phb[lr][kb * 32 + lg * 8];
        bf16x8 b0 = *(const bf16x8*)&Bg2[((size_t)(kb * 16 + wv_ * 4 + 0) * 64 + l) * 8];
        bf16x8 b1 = *(const bf16x8*)&Bg2[((size_t)(kb * 16 + wv_ * 4 + 1) * 64 + l) * 8];
        bf16x8 b2 = *(const bf16x8*)&Bg2[((size_t)(kb * 16 + wv_ * 4 + 2) * 64 + l) * 8];
        bf16x8 b3 = *(const bf16x8*)&Bg2[((size_t)(kb * 16 + wv_ * 4 + 3) * 64 + l) * 8];
        a0 = __builtin_amdgcn_mfma_f32_16x16x32_bf16(af, b0, a0, 0, 0, 0);
        a1 = __builtin_amdgcn_mfma_f32_16x16x32_bf16(af, b1, a1, 0, 0, 0);
        a2 = __builtin_amdgcn_mfma_f32_16x16x32_bf16(af, b2, a2, 0, 0, 0);
        a3 = __builtin_amdgcn_mfma_f32_16x16x32_bf16(af, b3, a3, 0, 0, 0);
    }
#pragma unroll
    for (int t = 0; t < 4; ++t) {
        const f32x4 av4 = (t == 0) ? a0 : (t == 1) ? a1 : (t == 2) ? a2 : a3;
        int col = (wv_ * 4 + t) * 16 + lr;
        float bb = g2b[col];
#pragma unroll
        for (int r = 0; r < 4; ++r)
            posb[lg * 4 + r][col] = f2bu(bf16r(av4[r] + bb));
    }
    __syncthreads();

    // softmax over K + weighted sum (bit-identical per-thread chain to r11)
    float av[16];
#pragma unroll
    for (int kk = 0; kk < 16; ++kk) av[kk] = bu2f(posb[kk][c]) * 0.0625f;
    float m = av[0];
#pragma unroll
    for (int kk = 1; kk < 16; ++kk) m = fmaxf(m, av[kk]);
    float e[16];
    float s = 0.f;
#pragma unroll
    for (int kk = 0; kk < 16; ++kk) {
        e[kk] = bf16r(expf(av[kk] - m));
        s += e[kk];
    }
#pragma unroll
    for (int kk = 0; kk < 16; ++kk) e[kk] = bf16r(e[kk] / s);
    float rr = 0.f;
#pragma unroll
    for (int kk = 0; kk < 16; ++kk) {
        float vp = bf16r(vf[kk] + posr[kk]);
        rr = fmaf(e[kk], vp, rr);
    }
    res[(size_t)bn * 256 + c] = bf16r(rr);
}

// ---------------------------------------------------------------------------
extern "C" void kernel_launch(void* const* d_in, const int* in_sizes, int n_in,
                              void* d_out, int out_size, void* d_ws, size_t ws_size,
                              hipStream_t stream)
{
    const float* xyz1     = (const float*)d_in[0];
    const float* points1  = (const float*)d_in[1];
    const float* xyz2     = (const float*)d_in[2];
    const float* points2  = (const float*)d_in[3];
    const float* up_w1    = (const float*)d_in[4];
    const float* up_b1    = (const float*)d_in[5];
    const float* up_w2    = (const float*)d_in[6];
    const float* up_b2    = (const float*)d_in[7];
    const float* fc1_w    = (const float*)d_in[8];
    const float* fc1_b    = (const float*)d_in[9];
    const float* fc2_w    = (const float*)d_in[10];
    const float* fc2_b    = (const float*)d_in[11];
    const float* delta_w1 = (const float*)d_in[12];
    const float* delta_b1 = (const float*)d_in[13];
    const float* delta_w2 = (const float*)d_in[14];
    const float* delta_b2 = (const float*)d_in[15];
    const float* gamma_w1 = (const float*)d_in[16];
    const float* gamma_b1 = (const float*)d_in[17];
    const float* gamma_w2 = (const float*)d_in[18];
    const float* gamma_b2 = (const float*)d_in[19];
    const float* wq       = (const float*)d_in[20];
    const float* wk       = (const float*)d_in[21];
    const float* wv       = (const float*)d_in[22];

    float* ws = (float*)d_ws;
    float* f1    = ws;
    float* feats = f1 + (size_t)BB * N1 * 256;
    float* x     = feats + (size_t)BB * N2 * 256;
    float* qb    = x + (size_t)BB * N2 * 256;
    float* kb    = qb + (size_t)BB * N2 * 256;
    float* vb    = kb + (size_t)BB * N2 * 256;
    int*   idx3  = (int*)(vb + (size_t)BB * N2 * 256);
    float* w3    = (float*)(idx3 + (size_t)BB * N2 * 3);
    int*   knn   = (int*)(w3 + (size_t)BB * N2 * 3);
    unsigned short* Bd2 = (unsigned short*)(knn + (size_t)BB * N2 * 16);
    unsigned short* Bg1 = Bd2 + 65536;
    unsigned short* Bg2 = Bg1 + 65536;
    float* resb  = x;   // x dead after q/k/v
    float* prbuf = qb;  // qb region reused as pre-rounded points scratch

    float* out = (float*)d_out;
    hipMemcpyAsync(out, xyz2, (size_t)BB * N2 * 3 * sizeof(float),
                   hipMemcpyDeviceToDevice, stream);

    const float BN = (float)(1.0 / sqrt(1.0 + 1e-5));

    // one-time weight swizzles for the MFMA chains
    swizzleW<<<32, 256, 0, stream>>>(delta_w2, Bd2);
    swizzleW<<<32, 256, 0, stream>>>(gamma_w1, Bg1);
    swizzleW<<<32, 256, 0, stream>>>(gamma_w2, Bg2);

    // pre-round points2 -> prbuf; f2 = relu(bf16(points2) @ bf16(up_w2) * bn)
    roundcopy<<<2048, 256, 0, stream>>>(points2, prbuf, BB * N2 * CC);
    gemm16<CC, true><<<BB * N2 / 16, 256, 0, stream>>>(prbuf, up_w2, up_b2, nullptr, BN, feats);
    // pre-round points1 -> prbuf; f1 = relu(bf16(points1) @ bf16(up_w1) * bn)
    roundcopy<<<2048, 256, 0, stream>>>(points1, prbuf, BB * N1 * CIN);
    gemm16<CIN, true><<<BB * N1 / 16, 256, 0, stream>>>(prbuf, up_w1, up_b1, nullptr, BN, f1);
    // selection on raw fp32 coords (bit-identical)
    nn3_kernel<<<BB * 16, 256, 0, stream>>>(xyz1, xyz2, idx3, w3);
    interp_kernel<<<BB * N2, 256, 0, stream>>>(f1, idx3, w3, feats);
    // x = bf16r(feats @ bf16(fc1_w))
    gemm16<CC, false><<<BB * N2 / 16, 256, 0, stream>>>(feats, fc1_w, fc1_b, nullptr, 1.f, x);
    // q/k/v
    gemm16<CC, false><<<BB * N2 / 16, 256, 0, stream>>>(x, wq, nullptr, nullptr, 1.f, qb);
    gemm16<CC, false><<<BB * N2 / 16, 256, 0, stream>>>(x, wk, nullptr, nullptr, 1.f, kb);
    gemm16<CC, false><<<BB * N2 / 16, 256, 0, stream>>>(x, wv, nullptr, nullptr, 1.f, vb);
    knn_kernel<<<BB * 64, 256, 0, stream>>>(xyz2, knn);
    // MFMA attention
    attn_mfma<<<BB * N2, 256, 0, stream>>>(xyz2, qb, kb, vb, knn,
                                           delta_w1, delta_b1, delta_b2, gamma_b1, gamma_b2,
                                           Bd2, Bg1, Bg2, resb);
    // out1 = bf16r(bf16r(resb @ bf16(fc2_w)) + feats)
    gemm16<CC, false><<<BB * N2 / 16, 256, 0, stream>>>(resb, fc2_w, fc2_b, feats, 1.f,
                                                        out + (size_t)BB * N2 * 3);
}

// Round 13
// 838.244 us; speedup vs baseline: 3.0808x; 1.3825x over previous
//
#include <hip/hip_runtime.h>
#include <hip/hip_bf16.h>
#include <math.h>
#include <float.h>

#define BB   4
#define N1   1024
#define N2   4096
#define CIN  512
#define CC   256
#define DM   256
#define KNNK 16

typedef __attribute__((ext_vector_type(8))) short bf16x8;
typedef __attribute__((ext_vector_type(4))) float f32x4;

__device__ __forceinline__ float bf16r(float x) {
    return __bfloat162float(__float2bfloat16(x));
}
__device__ __forceinline__ unsigned short f2bu(float x) {
    __hip_bfloat16 h = __float2bfloat16(x);
    return *reinterpret_cast<unsigned short*>(&h);
}
__device__ __forceinline__ float bu2f(unsigned short u) {
    __hip_bfloat16 h = *reinterpret_cast<__hip_bfloat16*>(&u);
    return __bfloat162float(h);
}

// Swizzle W[K][256] fp32 row-major -> bf16 MFMA-B-frag layout:
// B[((kb*16+tile)*64+l)*8 + i] = bf16(W[kb*32+(l>>4)*8+i][tile*16+(l&15)])
__global__ __launch_bounds__(256) void swizzleW(
    const float* __restrict__ W, unsigned short* __restrict__ B, int K)
{
    int idx = blockIdx.x * 256 + threadIdx.x;
    int total = (K >> 5) << 10;
    if (idx >= total) return;
    int l = idx & 63;
    int tile = (idx >> 6) & 15;
    int kb = idx >> 10;
    int col = tile * 16 + (l & 15);
    int k0 = kb * 32 + ((l >> 4) << 3);
#pragma unroll
    for (int i = 0; i < 8; ++i)
        B[(size_t)idx * 8 + i] = f2bu(W[(size_t)(k0 + i) * 256 + col]);
}

// ---------------------------------------------------------------------------
// MFMA GEMM: Y[row,col] = chain(acc -> +bias -> *bn -> relu -> +resid), all
// bf16-rounded at the same points as the scalar gemm16. 64-row tile per
// block (4 waves x 16 rows), N=256 fixed, X converted bf16 at LDS store.
// ---------------------------------------------------------------------------
template<int KD, bool RELU, bool BN_, bool RESID>
__global__ __launch_bounds__(256) void gemm_mfma(
    const float* __restrict__ X, const unsigned short* __restrict__ Bw,
    const float* __restrict__ bias, const float* __restrict__ resid,
    float scale, float* __restrict__ Y)
{
    const int c = threadIdx.x;
    const int l = c & 63, wv_ = c >> 6;
    const int lr = l & 15, lg = l >> 4;
    const int row0 = blockIdx.x * 64;
    __shared__ __align__(16) unsigned short As[64][72];

    f32x4 acc[16];
#pragma unroll
    for (int t = 0; t < 16; ++t) acc[t] = (f32x4){0.f, 0.f, 0.f, 0.f};

    const int rs = c >> 2, c0 = (c & 3) * 16;   // staging: row rs, 16 cols
    for (int ks = 0; ks < KD / 64; ++ks) {
        const float* src = X + (size_t)(row0 + rs) * KD + ks * 64 + c0;
#pragma unroll
        for (int i = 0; i < 16; i += 4) {
            float4 v = *(const float4*)(src + i);
            As[rs][c0 + i + 0] = f2bu(v.x);
            As[rs][c0 + i + 1] = f2bu(v.y);
            As[rs][c0 + i + 2] = f2bu(v.z);
            As[rs][c0 + i + 3] = f2bu(v.w);
        }
        __syncthreads();
#pragma unroll
        for (int kbl = 0; kbl < 2; ++kbl) {
            int kb = ks * 2 + kbl;
            bf16x8 af = *(const bf16x8*)&As[wv_ * 16 + lr][kbl * 32 + lg * 8];
#pragma unroll
            for (int t = 0; t < 16; ++t) {
                bf16x8 bf = *(const bf16x8*)&Bw[((size_t)(kb * 16 + t) * 64 + l) * 8];
                acc[t] = __builtin_amdgcn_mfma_f32_16x16x32_bf16(af, bf, acc[t], 0, 0, 0);
            }
        }
        __syncthreads();
    }
#pragma unroll
    for (int t = 0; t < 16; ++t) {
        int col = t * 16 + lr;
        float bb = bias ? bias[col] : 0.f;
#pragma unroll
        for (int r = 0; r < 4; ++r) {
            size_t row = row0 + wv_ * 16 + lg * 4 + r;
            float v = bf16r(acc[t][r]);
            v = bf16r(v + bb);
            if (BN_) v = bf16r(v * scale);
            if (RELU) v = fmaxf(v, 0.f);
            if (RESID) v = bf16r(v + resid[row * 256 + col]);
            Y[row * 256 + col] = v;
        }
    }
}

// ---- faithful fp32 distance (selection on RAW fp32 coords) ---------------
__device__ __forceinline__ float norm2_ref(float x, float y, float z) {
    return __fadd_rn(__fadd_rn(__fmul_rn(x, x), __fmul_rn(y, y)), __fmul_rn(z, z));
}
__device__ __forceinline__ float dist_ref(float sa, float nb,
                                          float ax, float ay, float az,
                                          float bx, float by, float bz) {
    float dot = __fadd_rn(__fadd_rn(__fmul_rn(ax, bx), __fmul_rn(ay, by)),
                          __fmul_rn(az, bz));
    return __fsub_rn(__fadd_rn(sa, nb), __fmul_rn(2.f, dot));
}

// ---------------------------------------------------------------------------
// 3-NN (unchanged — bit-identical selection)
// ---------------------------------------------------------------------------
__global__ __launch_bounds__(256) void nn3_kernel(
    const float* __restrict__ xyz1, const float* __restrict__ xyz2,
    int* __restrict__ idx3, float* __restrict__ w3)
{
    const int b = blockIdx.x >> 4;
    const int n = ((blockIdx.x & 15) << 8) + threadIdx.x;
    __shared__ float sx[N1], sy[N1], sz[N1], snb[N1];
    for (int i = threadIdx.x; i < N1; i += 256) {
        const float* p = xyz1 + ((size_t)b * N1 + i) * 3;
        float x = p[0], y = p[1], z = p[2];
        sx[i] = x; sy[i] = y; sz[i] = z;
        snb[i] = norm2_ref(x, y, z);
    }
    __syncthreads();
    const float* pq = xyz2 + ((size_t)b * N2 + n) * 3;
    const float ax = pq[0], ay = pq[1], az = pq[2];
    const float sa = norm2_ref(ax, ay, az);
    float d0 = FLT_MAX, d1 = FLT_MAX, d2 = FLT_MAX;
    int i0 = 0, i1 = 0, i2 = 0;
    for (int j = 0; j < N1; ++j) {
        float dist = dist_ref(sa, snb[j], ax, ay, az, sx[j], sy[j], sz[j]);
        if (dist < d2) {
            if (dist < d1) {
                d2 = d1; i2 = i1;
                if (dist < d0) { d1 = d0; i1 = i0; d0 = dist; i0 = j; }
                else           { d1 = dist; i1 = j; }
            } else { d2 = dist; i2 = j; }
        }
    }
    float r0 = __fdiv_rn(1.f, __fadd_rn(d0, 1e-8f));
    float r1 = __fdiv_rn(1.f, __fadd_rn(d1, 1e-8f));
    float r2 = __fdiv_rn(1.f, __fadd_rn(d2, 1e-8f));
    float s  = __fadd_rn(__fadd_rn(r0, r1), r2);
    size_t o = ((size_t)b * N2 + n) * 3;
    idx3[o] = i0; idx3[o + 1] = i1; idx3[o + 2] = i2;
    w3[o]     = __fdiv_rn(r0, s);
    w3[o + 1] = __fdiv_rn(r1, s);
    w3[o + 2] = __fdiv_rn(r2, s);
}

// feats[bn,c] = bf16r( bf16r(fp32_sum w_i*f1_i) + f2 )  (unchanged)
__global__ __launch_bounds__(256) void interp_kernel(
    const float* __restrict__ f1, const int* __restrict__ idx3,
    const float* __restrict__ w3, float* __restrict__ feats)
{
    const int bn = blockIdx.x;
    const int b = bn >> 12;
    const int c = threadIdx.x;
    size_t o = (size_t)bn * 3;
    int i0 = idx3[o], i1 = idx3[o + 1], i2 = idx3[o + 2];
    float w0 = w3[o], w1 = w3[o + 1], w2 = w3[o + 2];
    const float* f1b = f1 + (size_t)b * N1 * 256;
    float itp = w0 * f1b[(size_t)i0 * 256 + c]
              + w1 * f1b[(size_t)i1 * 256 + c]
              + w2 * f1b[(size_t)i2 * 256 + c];
    feats[(size_t)bn * 256 + c] = bf16r(bf16r(itp) + feats[(size_t)bn * 256 + c]);
}

// ---------------------------------------------------------------------------
// KNN top-16 (unchanged — bit-identical selection)
// ---------------------------------------------------------------------------
__global__ __launch_bounds__(256) void knn_kernel(
    const float* __restrict__ xyz2, int* __restrict__ knn_out)
{
    const int b = blockIdx.x >> 6;
    const int q0 = (blockIdx.x & 63) << 6;
    const int tid = threadIdx.x;
    const int ql = tid >> 2, r = tid & 3;
    const int n = q0 + ql;
    __shared__ float sx[N2], sy[N2], sz[N2], sn[N2];
    __shared__ float sd[64][4][16];
    __shared__ int   si[64][4][16];
    for (int i = tid; i < N2; i += 256) {
        const float* p = xyz2 + ((size_t)b * N2 + i) * 3;
        float x = p[0], y = p[1], z = p[2];
        sx[i] = x; sy[i] = y; sz[i] = z;
        sn[i] = norm2_ref(x, y, z);
    }
    __syncthreads();
    const float ax = sx[n], ay = sy[n], az = sz[n];
    const float sa = sn[n];
    float d[16]; int id[16];
#pragma unroll
    for (int s = 0; s < 16; ++s) { d[s] = FLT_MAX; id[s] = 0; }
    const int jbase = r << 10;
    for (int jj = 0; jj < 1024; ++jj) {
        int j = jbase + jj;
        float dist = dist_ref(sa, sn[j], ax, ay, az, sx[j], sy[j], sz[j]);
        if (dist < d[15]) {
#pragma unroll
            for (int s = 15; s >= 0; --s) {
                bool shift = (s > 0) && (dist < d[s - 1]);
                bool place = (dist < d[s]) && !shift;
                float nd = shift ? d[s - 1] : (place ? dist : d[s]);
                int   ni = shift ? id[s - 1] : (place ? j : id[s]);
                d[s] = nd; id[s] = ni;
            }
        }
    }
#pragma unroll
    for (int s = 0; s < 16; ++s) { sd[ql][r][s] = d[s]; si[ql][r][s] = id[s]; }
    __syncthreads();
    if (r == 0) {
        int p0 = 0, p1 = 0, p2 = 0, p3 = 0;
        size_t ob = ((size_t)b * N2 + n) * 16;
        for (int o = 0; o < 16; ++o) {
            float h0 = (p0 < 16) ? sd[ql][0][p0] : FLT_MAX;
            float h1 = (p1 < 16) ? sd[ql][1][p1] : FLT_MAX;
            float h2 = (p2 < 16) ? sd[ql][2][p2] : FLT_MAX;
            float h3 = (p3 < 16) ? sd[ql][3][p3] : FLT_MAX;
            int br = 0; float bd = h0;
            if (h1 < bd) { bd = h1; br = 1; }
            if (h2 < bd) { bd = h2; br = 2; }
            if (h3 < bd) { bd = h3; br = 3; }
            int bi;
            if (br == 0)      { bi = si[ql][0][p0]; ++p0; }
            else if (br == 1) { bi = si[ql][1][p1]; ++p1; }
            else if (br == 2) { bi = si[ql][2][p2]; ++p2; }
            else              { bi = si[ql][3][p3]; ++p3; }
            knn_out[ob + o] = bi;
        }
    }
}

// ---------------------------------------------------------------------------
// MFMA attention (unchanged from round 12 — passed with absmax 0.125)
// ---------------------------------------------------------------------------
__global__ __launch_bounds__(256) void attn_mfma(
    const float* __restrict__ xyz2, const float* __restrict__ qg,
    const float* __restrict__ kg, const float* __restrict__ vg,
    const int* __restrict__ knn,
    const float* __restrict__ d1w, const float* __restrict__ d1b,
    const float* __restrict__ d2b, const float* __restrict__ g1b,
    const float* __restrict__ g2b,
    const unsigned short* __restrict__ Bd2,
    const unsigned short* __restrict__ Bg1,
    const unsigned short* __restrict__ Bg2,
    float* __restrict__ res)
{
    const int bn = blockIdx.x;
    const int b = bn >> 12;
    const int c = threadIdx.x;
    const int l = c & 63, wv_ = c >> 6;
    const int lr = l & 15, lg = l >> 4;

    __shared__ __align__(16) unsigned short phb[16][264];
    __shared__ __align__(16) unsigned short posb[16][264];
    __shared__ int   knn_s[16];
    __shared__ float relx[16], rely[16], relz[16];

    if (c < 16) {
        int idx = knn[(size_t)bn * 16 + c];
        knn_s[c] = idx;
        const float* pq = xyz2 + (size_t)bn * 3;
        const float* pk = xyz2 + ((size_t)b * N2 + idx) * 3;
        relx[c] = bf16r(pq[0] - pk[0]);
        rely[c] = bf16r(pq[1] - pk[1]);
        relz[c] = bf16r(pq[2] - pk[2]);
    }
    __syncthreads();

    const size_t basebc = (size_t)b * N2 * 256;
    float kf[16], vf[16];
#pragma unroll
    for (int kk = 0; kk < 16; ++kk) {
        int row = knn_s[kk];
        kf[kk] = kg[basebc + (size_t)row * 256 + c];
        vf[kk] = vg[basebc + (size_t)row * 256 + c];
    }
    float qv = qg[(size_t)bn * 256 + c];

    {
        float w0 = bf16r(d1w[c]), w1 = bf16r(d1w[256 + c]), w2 = bf16r(d1w[512 + c]);
        float bb = d1b[c];
#pragma unroll
        for (int kk = 0; kk < 16; ++kk) {
            float v = fmaf(relx[kk], w0, fmaf(rely[kk], w1, fmaf(relz[kk], w2, bb)));
            phb[kk][c] = f2bu(fmaxf(bf16r(v), 0.f));
        }
    }
    __syncthreads();

    f32x4 a0 = {0.f,0.f,0.f,0.f}, a1 = a0, a2 = a0, a3 = a0;
    for (int kb = 0; kb < 8; ++kb) {
        bf16x8 af = *(const bf16x8*)&phb[lr][kb * 32 + lg * 8];
        bf16x8 b0 = *(const bf16x8*)&Bd2[((size_t)(kb * 16 + wv_ * 4 + 0) * 64 + l) * 8];
        bf16x8 b1 = *(const bf16x8*)&Bd2[((size_t)(kb * 16 + wv_ * 4 + 1) * 64 + l) * 8];
        bf16x8 b2 = *(const bf16x8*)&Bd2[((size_t)(kb * 16 + wv_ * 4 + 2) * 64 + l) * 8];
        bf16x8 b3 = *(const bf16x8*)&Bd2[((size_t)(kb * 16 + wv_ * 4 + 3) * 64 + l) * 8];
        a0 = __builtin_amdgcn_mfma_f32_16x16x32_bf16(af, b0, a0, 0, 0, 0);
        a1 = __builtin_amdgcn_mfma_f32_16x16x32_bf16(af, b1, a1, 0, 0, 0);
        a2 = __builtin_amdgcn_mfma_f32_16x16x32_bf16(af, b2, a2, 0, 0, 0);
        a3 = __builtin_amdgcn_mfma_f32_16x16x32_bf16(af, b3, a3, 0, 0, 0);
    }
#pragma unroll
    for (int t = 0; t < 4; ++t) {
        const f32x4 av4 = (t == 0) ? a0 : (t == 1) ? a1 : (t == 2) ? a2 : a3;
        int col = (wv_ * 4 + t) * 16 + lr;
        float bb = d2b[col];
#pragma unroll
        for (int r = 0; r < 4; ++r)
            posb[lg * 4 + r][col] = f2bu(bf16r(av4[r] + bb));
    }
    __syncthreads();

    float posr[16];
#pragma unroll
    for (int kk = 0; kk < 16; ++kk) posr[kk] = bu2f(posb[kk][c]);
#pragma unroll
    for (int kk = 0; kk < 16; ++kk)
        phb[kk][c] = f2bu(bf16r(bf16r(qv - kf[kk]) + posr[kk]));
    __syncthreads();

    a0 = (f32x4){0.f,0.f,0.f,0.f}; a1 = a0; a2 = a0; a3 = a0;
    for (int kb = 0; kb < 8; ++kb) {
        bf16x8 af = *(const bf16x8*)&phb[lr][kb * 32 + lg * 8];
        bf16x8 b0 = *(const bf16x8*)&Bg1[((size_t)(kb * 16 + wv_ * 4 + 0) * 64 + l) * 8];
        bf16x8 b1 = *(const bf16x8*)&Bg1[((size_t)(kb * 16 + wv_ * 4 + 1) * 64 + l) * 8];
        bf16x8 b2 = *(const bf16x8*)&Bg1[((size_t)(kb * 16 + wv_ * 4 + 2) * 64 + l) * 8];
        bf16x8 b3 = *(const bf16x8*)&Bg1[((size_t)(kb * 16 + wv_ * 4 + 3) * 64 + l) * 8];
        a0 = __builtin_amdgcn_mfma_f32_16x16x32_bf16(af, b0, a0, 0, 0, 0);
        a1 = __builtin_amdgcn_mfma_f32_16x16x32_bf16(af, b1, a1, 0, 0, 0);
        a2 = __builtin_amdgcn_mfma_f32_16x16x32_bf16(af, b2, a2, 0, 0, 0);
        a3 = __builtin_amdgcn_mfma_f32_16x16x32_bf16(af, b3, a3, 0, 0, 0);
    }
    __syncthreads();
#pragma unroll
    for (int t = 0; t < 4; ++t) {
        const f32x4 av4 = (t == 0) ? a0 : (t == 1) ? a1 : (t == 2) ? a2 : a3;
        int col = (wv_ * 4 + t) * 16 + lr;
        float bb = g1b[col];
#pragma unroll
        for (int r = 0; r < 4; ++r)
            phb[lg * 4 + r][col] = f2bu(fmaxf(bf16r(av4[r] + bb), 0.f));
    }
    __syncthreads();

    a0 = (f32x4){0.f,0.f,0.f,0.f}; a1 = a0; a2 = a0; a3 = a0;
    for (int kb = 0; kb < 8; ++kb) {
        bf16x8 af = *(const bf16x8*)&phb[lr][kb * 32 + lg * 8];
        bf16x8 b0 = *(const bf16x8*)&Bg2[((size_t)(kb * 16 + wv_ * 4 + 0) * 64 + l) * 8];
        bf16x8 b1 = *(const bf16x8*)&Bg2[((size_t)(kb * 16 + wv_ * 4 + 1) * 64 + l) * 8];
        bf16x8 b2 = *(const bf16x8*)&Bg2[((size_t)(kb * 16 + wv_ * 4 + 2) * 64 + l) * 8];
        bf16x8 b3 = *(const bf16x8*)&Bg2[((size_t)(kb * 16 + wv_ * 4 + 3) * 64 + l) * 8];
        a0 = __builtin_amdgcn_mfma_f32_16x16x32_bf16(af, b0, a0, 0, 0, 0);
        a1 = __builtin_amdgcn_mfma_f32_16x16x32_bf16(af, b1, a1, 0, 0, 0);
        a2 = __builtin_amdgcn_mfma_f32_16x16x32_bf16(af, b2, a2, 0, 0, 0);
        a3 = __builtin_amdgcn_mfma_f32_16x16x32_bf16(af, b3, a3, 0, 0, 0);
    }
#pragma unroll
    for (int t = 0; t < 4; ++t) {
        const f32x4 av4 = (t == 0) ? a0 : (t == 1) ? a1 : (t == 2) ? a2 : a3;
        int col = (wv_ * 4 + t) * 16 + lr;
        float bb = g2b[col];
#pragma unroll
        for (int r = 0; r < 4; ++r)
            posb[lg * 4 + r][col] = f2bu(bf16r(av4[r] + bb));
    }
    __syncthreads();

    float av[16];
#pragma unroll
    for (int kk = 0; kk < 16; ++kk) av[kk] = bu2f(posb[kk][c]) * 0.0625f;
    float m = av[0];
#pragma unroll
    for (int kk = 1; kk < 16; ++kk) m = fmaxf(m, av[kk]);
    float e[16];
    float s = 0.f;
#pragma unroll
    for (int kk = 0; kk < 16; ++kk) {
        e[kk] = bf16r(expf(av[kk] - m));
        s += e[kk];
    }
#pragma unroll
    for (int kk = 0; kk < 16; ++kk) e[kk] = bf16r(e[kk] / s);
    float rr = 0.f;
#pragma unroll
    for (int kk = 0; kk < 16; ++kk) {
        float vp = bf16r(vf[kk] + posr[kk]);
        rr = fmaf(e[kk], vp, rr);
    }
    res[(size_t)bn * 256 + c] = bf16r(rr);
}

// ---------------------------------------------------------------------------
extern "C" void kernel_launch(void* const* d_in, const int* in_sizes, int n_in,
                              void* d_out, int out_size, void* d_ws, size_t ws_size,
                              hipStream_t stream)
{
    const float* xyz1     = (const float*)d_in[0];
    const float* points1  = (const float*)d_in[1];
    const float* xyz2     = (const float*)d_in[2];
    const float* points2  = (const float*)d_in[3];
    const float* up_w1    = (const float*)d_in[4];
    const float* up_b1    = (const float*)d_in[5];
    const float* up_w2    = (const float*)d_in[6];
    const float* up_b2    = (const float*)d_in[7];
    const float* fc1_w    = (const float*)d_in[8];
    const float* fc1_b    = (const float*)d_in[9];
    const float* fc2_w    = (const float*)d_in[10];
    const float* fc2_b    = (const float*)d_in[11];
    const float* delta_w1 = (const float*)d_in[12];
    const float* delta_b1 = (const float*)d_in[13];
    const float* delta_w2 = (const float*)d_in[14];
    const float* delta_b2 = (const float*)d_in[15];
    const float* gamma_w1 = (const float*)d_in[16];
    const float* gamma_b1 = (const float*)d_in[17];
    const float* gamma_w2 = (const float*)d_in[18];
    const float* gamma_b2 = (const float*)d_in[19];
    const float* wq       = (const float*)d_in[20];
    const float* wk       = (const float*)d_in[21];
    const float* wv       = (const float*)d_in[22];

    float* ws = (float*)d_ws;
    float* f1    = ws;
    float* feats = f1 + (size_t)BB * N1 * 256;
    float* x     = feats + (size_t)BB * N2 * 256;
    float* qb    = x + (size_t)BB * N2 * 256;
    float* kb    = qb + (size_t)BB * N2 * 256;
    float* vb    = kb + (size_t)BB * N2 * 256;
    int*   idx3  = (int*)(vb + (size_t)BB * N2 * 256);
    float* w3    = (float*)(idx3 + (size_t)BB * N2 * 3);
    int*   knn   = (int*)(w3 + (size_t)BB * N2 * 3);
    unsigned short* Bd2  = (unsigned short*)(knn + (size_t)BB * N2 * 16);
    unsigned short* Bg1  = Bd2 + 65536;
    unsigned short* Bg2  = Bg1 + 65536;
    unsigned short* Bup1 = Bg2 + 65536;       // 512x256 -> 131072
    unsigned short* Bup2 = Bup1 + 131072;
    unsigned short* Bfc1 = Bup2 + 65536;
    unsigned short* Bfc2 = Bfc1 + 65536;
    unsigned short* Bq   = Bfc2 + 65536;
    unsigned short* Bk   = Bq + 65536;
    unsigned short* Bv   = Bk + 65536;
    float* resb = x;   // x dead after q/k/v

    float* out = (float*)d_out;
    hipMemcpyAsync(out, xyz2, (size_t)BB * N2 * 3 * sizeof(float),
                   hipMemcpyDeviceToDevice, stream);

    const float BN = (float)(1.0 / sqrt(1.0 + 1e-5));

    // one-time weight swizzles
    swizzleW<<<64, 256, 0, stream>>>(up_w1, Bup1, CIN);
    swizzleW<<<32, 256, 0, stream>>>(up_w2, Bup2, CC);
    swizzleW<<<32, 256, 0, stream>>>(fc1_w, Bfc1, CC);
    swizzleW<<<32, 256, 0, stream>>>(fc2_w, Bfc2, CC);
    swizzleW<<<32, 256, 0, stream>>>(wq, Bq, CC);
    swizzleW<<<32, 256, 0, stream>>>(wk, Bk, CC);
    swizzleW<<<32, 256, 0, stream>>>(wv, Bv, CC);
    swizzleW<<<32, 256, 0, stream>>>(delta_w2, Bd2, CC);
    swizzleW<<<32, 256, 0, stream>>>(gamma_w1, Bg1, CC);
    swizzleW<<<32, 256, 0, stream>>>(gamma_w2, Bg2, CC);

    // f2 = relu(bf16(points2) @ bf16(up_w2) * bn) -> feats
    gemm_mfma<CC, true, true, false><<<BB * N2 / 64, 256, 0, stream>>>(
        points2, Bup2, up_b2, nullptr, BN, feats);
    // f1 = relu(bf16(points1) @ bf16(up_w1) * bn)
    gemm_mfma<CIN, true, true, false><<<BB * N1 / 64, 256, 0, stream>>>(
        points1, Bup1, up_b1, nullptr, BN, f1);
    // selection on raw fp32 coords (bit-identical)
    nn3_kernel<<<BB * 16, 256, 0, stream>>>(xyz1, xyz2, idx3, w3);
    interp_kernel<<<BB * N2, 256, 0, stream>>>(f1, idx3, w3, feats);
    // x = bf16r(feats @ bf16(fc1_w))
    gemm_mfma<CC, false, false, false><<<BB * N2 / 64, 256, 0, stream>>>(
        feats, Bfc1, fc1_b, nullptr, 1.f, x);
    // q/k/v
    gemm_mfma<CC, false, false, false><<<BB * N2 / 64, 256, 0, stream>>>(
        x, Bq, nullptr, nullptr, 1.f, qb);
    gemm_mfma<CC, false, false, false><<<BB * N2 / 64, 256, 0, stream>>>(
        x, Bk, nullptr, nullptr, 1.f, kb);
    gemm_mfma<CC, false, false, false><<<BB * N2 / 64, 256, 0, stream>>>(
        x, Bv, nullptr, nullptr, 1.f, vb);
    knn_kernel<<<BB * 64, 256, 0, stream>>>(xyz2, knn);
    attn_mfma<<<BB * N2, 256, 0, stream>>>(xyz2, qb, kb, vb, knn,
                                           delta_w1, delta_b1, delta_b2, gamma_b1, gamma_b2,
                                           Bd2, Bg1, Bg2, resb);
    // out1 = bf16r(bf16r(resb @ bf16(fc2_w)) + feats)
    gemm_mfma<CC, false, false, true><<<BB * N2 / 64, 256, 0, stream>>>(
        resb, Bfc2, fc2_b, feats, 1.f, out + (size_t)BB * N2 * 3);
}

// Round 14
// 791.026 us; speedup vs baseline: 3.2647x; 1.0597x over previous
//
#include <hip/hip_runtime.h>
#include <hip/hip_bf16.h>
#include <math.h>
#include <float.h>

#define BB   4
#define N1   1024
#define N2   4096
#define CIN  512
#define CC   256
#define DM   256
#define KNNK 16

typedef __attribute__((ext_vector_type(8))) short bf16x8;
typedef __attribute__((ext_vector_type(4))) float f32x4;

__device__ __forceinline__ float bf16r(float x) {
    return __bfloat162float(__float2bfloat16(x));
}
__device__ __forceinline__ unsigned short f2bu(float x) {
    __hip_bfloat16 h = __float2bfloat16(x);
    return *reinterpret_cast<unsigned short*>(&h);
}
__device__ __forceinline__ float bu2f(unsigned short u) {
    __hip_bfloat16 h = *reinterpret_cast<__hip_bfloat16*>(&u);
    return __bfloat162float(h);
}

// Swizzle W[K][256] fp32 row-major -> bf16 MFMA-B-frag layout
__global__ __launch_bounds__(256) void swizzleW(
    const float* __restrict__ W, unsigned short* __restrict__ B, int K)
{
    int idx = blockIdx.x * 256 + threadIdx.x;
    int total = (K >> 5) << 10;
    if (idx >= total) return;
    int l = idx & 63;
    int tile = (idx >> 6) & 15;
    int kb = idx >> 10;
    int col = tile * 16 + (l & 15);
    int k0 = kb * 32 + ((l >> 4) << 3);
#pragma unroll
    for (int i = 0; i < 8; ++i)
        B[(size_t)idx * 8 + i] = f2bu(W[(size_t)(k0 + i) * 256 + col]);
}

// ---------------------------------------------------------------------------
// MFMA GEMM, N-split: each block computes 64 rows x NT*16 cols. Per-element
// arithmetic identical to round-13 (same K order, same rounding chain).
// ---------------------------------------------------------------------------
template<int KD, int NT, bool RELU, bool BN_, bool RESID>
__global__ __launch_bounds__(256) void gemm_mfma(
    const float* __restrict__ X, const unsigned short* __restrict__ Bw,
    const float* __restrict__ bias, const float* __restrict__ resid,
    float scale, float* __restrict__ Y)
{
    const int NSPLIT = 16 / NT;
    const int c = threadIdx.x;
    const int l = c & 63, wv_ = c >> 6;
    const int lr = l & 15, lg = l >> 4;
    const int row0 = (blockIdx.x / NSPLIT) * 64;
    const int tb = (blockIdx.x % NSPLIT) * NT;
    __shared__ __align__(16) unsigned short As[64][72];

    f32x4 acc[NT];
#pragma unroll
    for (int t = 0; t < NT; ++t) acc[t] = (f32x4){0.f, 0.f, 0.f, 0.f};

    const int rs = c >> 2, c0 = (c & 3) * 16;
    for (int ks = 0; ks < KD / 64; ++ks) {
        const float* src = X + (size_t)(row0 + rs) * KD + ks * 64 + c0;
#pragma unroll
        for (int i = 0; i < 16; i += 4) {
            float4 v = *(const float4*)(src + i);
            As[rs][c0 + i + 0] = f2bu(v.x);
            As[rs][c0 + i + 1] = f2bu(v.y);
            As[rs][c0 + i + 2] = f2bu(v.z);
            As[rs][c0 + i + 3] = f2bu(v.w);
        }
        __syncthreads();
#pragma unroll
        for (int kbl = 0; kbl < 2; ++kbl) {
            int kb = ks * 2 + kbl;
            bf16x8 af = *(const bf16x8*)&As[wv_ * 16 + lr][kbl * 32 + lg * 8];
#pragma unroll
            for (int t = 0; t < NT; ++t) {
                bf16x8 bf = *(const bf16x8*)&Bw[((size_t)(kb * 16 + tb + t) * 64 + l) * 8];
                acc[t] = __builtin_amdgcn_mfma_f32_16x16x32_bf16(af, bf, acc[t], 0, 0, 0);
            }
        }
        __syncthreads();
    }
#pragma unroll
    for (int t = 0; t < NT; ++t) {
        int col = (tb + t) * 16 + lr;
        float bb = bias ? bias[col] : 0.f;
#pragma unroll
        for (int r = 0; r < 4; ++r) {
            size_t row = row0 + wv_ * 16 + lg * 4 + r;
            float v = bf16r(acc[t][r]);
            v = bf16r(v + bb);
            if (BN_) v = bf16r(v * scale);
            if (RELU) v = fmaxf(v, 0.f);
            if (RESID) v = bf16r(v + resid[row * 256 + col]);
            Y[row * 256 + col] = v;
        }
    }
}

// ---------------------------------------------------------------------------
// Fused q/k/v GEMM: stages the x-tile once, applies 3 swizzled weight mats.
// N-split 2 (NT=8): acc = 3 x 8 frags. Per-element arithmetic identical.
// ---------------------------------------------------------------------------
__global__ __launch_bounds__(256) void qkv_mfma(
    const float* __restrict__ X,
    const unsigned short* __restrict__ Bq,
    const unsigned short* __restrict__ Bk,
    const unsigned short* __restrict__ Bv,
    float* __restrict__ Yq, float* __restrict__ Yk, float* __restrict__ Yv)
{
    const int NT = 8;
    const int c = threadIdx.x;
    const int l = c & 63, wv_ = c >> 6;
    const int lr = l & 15, lg = l >> 4;
    const int row0 = (blockIdx.x >> 1) * 64;
    const int tb = (blockIdx.x & 1) * NT;
    __shared__ __align__(16) unsigned short As[64][72];

    f32x4 aq[NT], ak[NT], av_[NT];
#pragma unroll
    for (int t = 0; t < NT; ++t) {
        aq[t] = (f32x4){0.f, 0.f, 0.f, 0.f};
        ak[t] = aq[t]; av_[t] = aq[t];
    }

    const int rs = c >> 2, c0 = (c & 3) * 16;
    for (int ks = 0; ks < CC / 64; ++ks) {
        const float* src = X + (size_t)(row0 + rs) * CC + ks * 64 + c0;
#pragma unroll
        for (int i = 0; i < 16; i += 4) {
            float4 v = *(const float4*)(src + i);
            As[rs][c0 + i + 0] = f2bu(v.x);
            As[rs][c0 + i + 1] = f2bu(v.y);
            As[rs][c0 + i + 2] = f2bu(v.z);
            As[rs][c0 + i + 3] = f2bu(v.w);
        }
        __syncthreads();
#pragma unroll
        for (int kbl = 0; kbl < 2; ++kbl) {
            int kb = ks * 2 + kbl;
            bf16x8 af = *(const bf16x8*)&As[wv_ * 16 + lr][kbl * 32 + lg * 8];
#pragma unroll
            for (int t = 0; t < NT; ++t) {
                size_t fo = ((size_t)(kb * 16 + tb + t) * 64 + l) * 8;
                bf16x8 bq = *(const bf16x8*)&Bq[fo];
                bf16x8 bk = *(const bf16x8*)&Bk[fo];
                bf16x8 bv = *(const bf16x8*)&Bv[fo];
                aq[t]  = __builtin_amdgcn_mfma_f32_16x16x32_bf16(af, bq, aq[t], 0, 0, 0);
                ak[t]  = __builtin_amdgcn_mfma_f32_16x16x32_bf16(af, bk, ak[t], 0, 0, 0);
                av_[t] = __builtin_amdgcn_mfma_f32_16x16x32_bf16(af, bv, av_[t], 0, 0, 0);
            }
        }
        __syncthreads();
    }
#pragma unroll
    for (int t = 0; t < NT; ++t) {
        int col = (tb + t) * 16 + lr;
#pragma unroll
        for (int r = 0; r < 4; ++r) {
            size_t row = row0 + wv_ * 16 + lg * 4 + r;
            Yq[row * 256 + col] = bf16r(bf16r(aq[t][r]));
            Yk[row * 256 + col] = bf16r(bf16r(ak[t][r]));
            Yv[row * 256 + col] = bf16r(bf16r(av_[t][r]));
        }
    }
}

// ---- faithful fp32 distance (selection on RAW fp32 coords) ---------------
__device__ __forceinline__ float norm2_ref(float x, float y, float z) {
    return __fadd_rn(__fadd_rn(__fmul_rn(x, x), __fmul_rn(y, y)), __fmul_rn(z, z));
}
__device__ __forceinline__ float dist_ref(float sa, float nb,
                                          float ax, float ay, float az,
                                          float bx, float by, float bz) {
    float dot = __fadd_rn(__fadd_rn(__fmul_rn(ax, bx), __fmul_rn(ay, by)),
                          __fmul_rn(az, bz));
    return __fsub_rn(__fadd_rn(sa, nb), __fmul_rn(2.f, dot));
}

// ---------------------------------------------------------------------------
// 3-NN (unchanged — bit-identical selection)
// ---------------------------------------------------------------------------
__global__ __launch_bounds__(256) void nn3_kernel(
    const float* __restrict__ xyz1, const float* __restrict__ xyz2,
    int* __restrict__ idx3, float* __restrict__ w3)
{
    const int b = blockIdx.x >> 4;
    const int n = ((blockIdx.x & 15) << 8) + threadIdx.x;
    __shared__ float sx[N1], sy[N1], sz[N1], snb[N1];
    for (int i = threadIdx.x; i < N1; i += 256) {
        const float* p = xyz1 + ((size_t)b * N1 + i) * 3;
        float x = p[0], y = p[1], z = p[2];
        sx[i] = x; sy[i] = y; sz[i] = z;
        snb[i] = norm2_ref(x, y, z);
    }
    __syncthreads();
    const float* pq = xyz2 + ((size_t)b * N2 + n) * 3;
    const float ax = pq[0], ay = pq[1], az = pq[2];
    const float sa = norm2_ref(ax, ay, az);
    float d0 = FLT_MAX, d1 = FLT_MAX, d2 = FLT_MAX;
    int i0 = 0, i1 = 0, i2 = 0;
    for (int j = 0; j < N1; ++j) {
        float dist = dist_ref(sa, snb[j], ax, ay, az, sx[j], sy[j], sz[j]);
        if (dist < d2) {
            if (dist < d1) {
                d2 = d1; i2 = i1;
                if (dist < d0) { d1 = d0; i1 = i0; d0 = dist; i0 = j; }
                else           { d1 = dist; i1 = j; }
            } else { d2 = dist; i2 = j; }
        }
    }
    float r0 = __fdiv_rn(1.f, __fadd_rn(d0, 1e-8f));
    float r1 = __fdiv_rn(1.f, __fadd_rn(d1, 1e-8f));
    float r2 = __fdiv_rn(1.f, __fadd_rn(d2, 1e-8f));
    float s  = __fadd_rn(__fadd_rn(r0, r1), r2);
    size_t o = ((size_t)b * N2 + n) * 3;
    idx3[o] = i0; idx3[o + 1] = i1; idx3[o + 2] = i2;
    w3[o]     = __fdiv_rn(r0, s);
    w3[o + 1] = __fdiv_rn(r1, s);
    w3[o + 2] = __fdiv_rn(r2, s);
}

// feats[bn,c] = bf16r( bf16r(fp32_sum w_i*f1_i) + f2 )  (unchanged)
__global__ __launch_bounds__(256) void interp_kernel(
    const float* __restrict__ f1, const int* __restrict__ idx3,
    const float* __restrict__ w3, float* __restrict__ feats)
{
    const int bn = blockIdx.x;
    const int b = bn >> 12;
    const int c = threadIdx.x;
    size_t o = (size_t)bn * 3;
    int i0 = idx3[o], i1 = idx3[o + 1], i2 = idx3[o + 2];
    float w0 = w3[o], w1 = w3[o + 1], w2 = w3[o + 2];
    const float* f1b = f1 + (size_t)b * N1 * 256;
    float itp = w0 * f1b[(size_t)i0 * 256 + c]
              + w1 * f1b[(size_t)i1 * 256 + c]
              + w2 * f1b[(size_t)i2 * 256 + c];
    feats[(size_t)bn * 256 + c] = bf16r(bf16r(itp) + feats[(size_t)bn * 256 + c]);
}

// ---------------------------------------------------------------------------
// KNN top-16 (unchanged — bit-identical selection)
// ---------------------------------------------------------------------------
__global__ __launch_bounds__(256) void knn_kernel(
    const float* __restrict__ xyz2, int* __restrict__ knn_out)
{
    const int b = blockIdx.x >> 6;
    const int q0 = (blockIdx.x & 63) << 6;
    const int tid = threadIdx.x;
    const int ql = tid >> 2, r = tid & 3;
    const int n = q0 + ql;
    __shared__ float sx[N2], sy[N2], sz[N2], sn[N2];
    __shared__ float sd[64][4][16];
    __shared__ int   si[64][4][16];
    for (int i = tid; i < N2; i += 256) {
        const float* p = xyz2 + ((size_t)b * N2 + i) * 3;
        float x = p[0], y = p[1], z = p[2];
        sx[i] = x; sy[i] = y; sz[i] = z;
        sn[i] = norm2_ref(x, y, z);
    }
    __syncthreads();
    const float ax = sx[n], ay = sy[n], az = sz[n];
    const float sa = sn[n];
    float d[16]; int id[16];
#pragma unroll
    for (int s = 0; s < 16; ++s) { d[s] = FLT_MAX; id[s] = 0; }
    const int jbase = r << 10;
    for (int jj = 0; jj < 1024; ++jj) {
        int j = jbase + jj;
        float dist = dist_ref(sa, sn[j], ax, ay, az, sx[j], sy[j], sz[j]);
        if (dist < d[15]) {
#pragma unroll
            for (int s = 15; s >= 0; --s) {
                bool shift = (s > 0) && (dist < d[s - 1]);
                bool place = (dist < d[s]) && !shift;
                float nd = shift ? d[s - 1] : (place ? dist : d[s]);
                int   ni = shift ? id[s - 1] : (place ? j : id[s]);
                d[s] = nd; id[s] = ni;
            }
        }
    }
#pragma unroll
    for (int s = 0; s < 16; ++s) { sd[ql][r][s] = d[s]; si[ql][r][s] = id[s]; }
    __syncthreads();
    if (r == 0) {
        int p0 = 0, p1 = 0, p2 = 0, p3 = 0;
        size_t ob = ((size_t)b * N2 + n) * 16;
        for (int o = 0; o < 16; ++o) {
            float h0 = (p0 < 16) ? sd[ql][0][p0] : FLT_MAX;
            float h1 = (p1 < 16) ? sd[ql][1][p1] : FLT_MAX;
            float h2 = (p2 < 16) ? sd[ql][2][p2] : FLT_MAX;
            float h3 = (p3 < 16) ? sd[ql][3][p3] : FLT_MAX;
            int br = 0; float bd = h0;
            if (h1 < bd) { bd = h1; br = 1; }
            if (h2 < bd) { bd = h2; br = 2; }
            if (h3 < bd) { bd = h3; br = 3; }
            int bi;
            if (br == 0)      { bi = si[ql][0][p0]; ++p0; }
            else if (br == 1) { bi = si[ql][1][p1]; ++p1; }
            else if (br == 2) { bi = si[ql][2][p2]; ++p2; }
            else              { bi = si[ql][3][p3]; ++p3; }
            knn_out[ob + o] = bi;
        }
    }
}

// ---------------------------------------------------------------------------
// MFMA attention (unchanged from round 12/13 — passed with absmax 0.125)
// ---------------------------------------------------------------------------
__global__ __launch_bounds__(256) void attn_mfma(
    const float* __restrict__ xyz2, const float* __restrict__ qg,
    const float* __restrict__ kg, const float* __restrict__ vg,
    const int* __restrict__ knn,
    const float* __restrict__ d1w, const float* __restrict__ d1b,
    const float* __restrict__ d2b, const float* __restrict__ g1b,
    const float* __restrict__ g2b,
    const unsigned short* __restrict__ Bd2,
    const unsigned short* __restrict__ Bg1,
    const unsigned short* __restrict__ Bg2,
    float* __restrict__ res)
{
    const int bn = blockIdx.x;
    const int b = bn >> 12;
    const int c = threadIdx.x;
    const int l = c & 63, wv_ = c >> 6;
    const int lr = l & 15, lg = l >> 4;

    __shared__ __align__(16) unsigned short phb[16][264];
    __shared__ __align__(16) unsigned short posb[16][264];
    __shared__ int   knn_s[16];
    __shared__ float relx[16], rely[16], relz[16];

    if (c < 16) {
        int idx = knn[(size_t)bn * 16 + c];
        knn_s[c] = idx;
        const float* pq = xyz2 + (size_t)bn * 3;
        const float* pk = xyz2 + ((size_t)b * N2 + idx) * 3;
        relx[c] = bf16r(pq[0] - pk[0]);
        rely[c] = bf16r(pq[1] - pk[1]);
        relz[c] = bf16r(pq[2] - pk[2]);
    }
    __syncthreads();

    const size_t basebc = (size_t)b * N2 * 256;
    float kf[16], vf[16];
#pragma unroll
    for (int kk = 0; kk < 16; ++kk) {
        int row = knn_s[kk];
        kf[kk] = kg[basebc + (size_t)row * 256 + c];
        vf[kk] = vg[basebc + (size_t)row * 256 + c];
    }
    float qv = qg[(size_t)bn * 256 + c];

    {
        float w0 = bf16r(d1w[c]), w1 = bf16r(d1w[256 + c]), w2 = bf16r(d1w[512 + c]);
        float bb = d1b[c];
#pragma unroll
        for (int kk = 0; kk < 16; ++kk) {
            float v = fmaf(relx[kk], w0, fmaf(rely[kk], w1, fmaf(relz[kk], w2, bb)));
            phb[kk][c] = f2bu(fmaxf(bf16r(v), 0.f));
        }
    }
    __syncthreads();

    f32x4 a0 = {0.f,0.f,0.f,0.f}, a1 = a0, a2 = a0, a3 = a0;
    for (int kb = 0; kb < 8; ++kb) {
        bf16x8 af = *(const bf16x8*)&phb[lr][kb * 32 + lg * 8];
        bf16x8 b0 = *(const bf16x8*)&Bd2[((size_t)(kb * 16 + wv_ * 4 + 0) * 64 + l) * 8];
        bf16x8 b1 = *(const bf16x8*)&Bd2[((size_t)(kb * 16 + wv_ * 4 + 1) * 64 + l) * 8];
        bf16x8 b2 = *(const bf16x8*)&Bd2[((size_t)(kb * 16 + wv_ * 4 + 2) * 64 + l) * 8];
        bf16x8 b3 = *(const bf16x8*)&Bd2[((size_t)(kb * 16 + wv_ * 4 + 3) * 64 + l) * 8];
        a0 = __builtin_amdgcn_mfma_f32_16x16x32_bf16(af, b0, a0, 0, 0, 0);
        a1 = __builtin_amdgcn_mfma_f32_16x16x32_bf16(af, b1, a1, 0, 0, 0);
        a2 = __builtin_amdgcn_mfma_f32_16x16x32_bf16(af, b2, a2, 0, 0, 0);
        a3 = __builtin_amdgcn_mfma_f32_16x16x32_bf16(af, b3, a3, 0, 0, 0);
    }
#pragma unroll
    for (int t = 0; t < 4; ++t) {
        const f32x4 av4 = (t == 0) ? a0 : (t == 1) ? a1 : (t == 2) ? a2 : a3;
        int col = (wv_ * 4 + t) * 16 + lr;
        float bb = d2b[col];
#pragma unroll
        for (int r = 0; r < 4; ++r)
            posb[lg * 4 + r][col] = f2bu(bf16r(av4[r] + bb));
    }
    __syncthreads();

    float posr[16];
#pragma unroll
    for (int kk = 0; kk < 16; ++kk) posr[kk] = bu2f(posb[kk][c]);
#pragma unroll
    for (int kk = 0; kk < 16; ++kk)
        phb[kk][c] = f2bu(bf16r(bf16r(qv - kf[kk]) + posr[kk]));
    __syncthreads();

    a0 = (f32x4){0.f,0.f,0.f,0.f}; a1 = a0; a2 = a0; a3 = a0;
    for (int kb = 0; kb < 8; ++kb) {
        bf16x8 af = *(const bf16x8*)&phb[lr][kb * 32 + lg * 8];
        bf16x8 b0 = *(const bf16x8*)&Bg1[((size_t)(kb * 16 + wv_ * 4 + 0) * 64 + l) * 8];
        bf16x8 b1 = *(const bf16x8*)&Bg1[((size_t)(kb * 16 + wv_ * 4 + 1) * 64 + l) * 8];
        bf16x8 b2 = *(const bf16x8*)&Bg1[((size_t)(kb * 16 + wv_ * 4 + 2) * 64 + l) * 8];
        bf16x8 b3 = *(const bf16x8*)&Bg1[((size_t)(kb * 16 + wv_ * 4 + 3) * 64 + l) * 8];
        a0 = __builtin_amdgcn_mfma_f32_16x16x32_bf16(af, b0, a0, 0, 0, 0);
        a1 = __builtin_amdgcn_mfma_f32_16x16x32_bf16(af, b1, a1, 0, 0, 0);
        a2 = __builtin_amdgcn_mfma_f32_16x16x32_bf16(af, b2, a2, 0, 0, 0);
        a3 = __builtin_amdgcn_mfma_f32_16x16x32_bf16(af, b3, a3, 0, 0, 0);
    }
    __syncthreads();
#pragma unroll
    for (int t = 0; t < 4; ++t) {
        const f32x4 av4 = (t == 0) ? a0 : (t == 1) ? a1 : (t == 2) ? a2 : a3;
        int col = (wv_ * 4 + t) * 16 + lr;
        float bb = g1b[col];
#pragma unroll
        for (int r = 0; r < 4; ++r)
            phb[lg * 4 + r][col] = f2bu(fmaxf(bf16r(av4[r] + bb), 0.f));
    }
    __syncthreads();

    a0 = (f32x4){0.f,0.f,0.f,0.f}; a1 = a0; a2 = a0; a3 = a0;
    for (int kb = 0; kb < 8; ++kb) {
        bf16x8 af = *(const bf16x8*)&phb[lr][kb * 32 + lg * 8];
        bf16x8 b0 = *(const bf16x8*)&Bg2[((size_t)(kb * 16 + wv_ * 4 + 0) * 64 + l) * 8];
        bf16x8 b1 = *(const bf16x8*)&Bg2[((size_t)(kb * 16 + wv_ * 4 + 1) * 64 + l) * 8];
        bf16x8 b2 = *(const bf16x8*)&Bg2[((size_t)(kb * 16 + wv_ * 4 + 2) * 64 + l) * 8];
        bf16x8 b3 = *(const bf16x8*)&Bg2[((size_t)(kb * 16 + wv_ * 4 + 3) * 64 + l) * 8];
        a0 = __builtin_amdgcn_mfma_f32_16x16x32_bf16(af, b0, a0, 0, 0, 0);
        a1 = __builtin_amdgcn_mfma_f32_16x16x32_bf16(af, b1, a1, 0, 0, 0);
        a2 = __builtin_amdgcn_mfma_f32_16x16x32_bf16(af, b2, a2, 0, 0, 0);
        a3 = __builtin_amdgcn_mfma_f32_16x16x32_bf16(af, b3, a3, 0, 0, 0);
    }
#pragma unroll
    for (int t = 0; t < 4; ++t) {
        const f32x4 av4 = (t == 0) ? a0 : (t == 1) ? a1 : (t == 2) ? a2 : a3;
        int col = (wv_ * 4 + t) * 16 + lr;
        float bb = g2b[col];
#pragma unroll
        for (int r = 0; r < 4; ++r)
            posb[lg * 4 + r][col] = f2bu(bf16r(av4[r] + bb));
    }
    __syncthreads();

    float av[16];
#pragma unroll
    for (int kk = 0; kk < 16; ++kk) av[kk] = bu2f(posb[kk][c]) * 0.0625f;
    float m = av[0];
#pragma unroll
    for (int kk = 1; kk < 16; ++kk) m = fmaxf(m, av[kk]);
    float e[16];
    float s = 0.f;
#pragma unroll
    for (int kk = 0; kk < 16; ++kk) {
        e[kk] = bf16r(expf(av[kk] - m));
        s += e[kk];
    }
#pragma unroll
    for (int kk = 0; kk < 16; ++kk) e[kk] = bf16r(e[kk] / s);
    float rr = 0.f;
#pragma unroll
    for (int kk = 0; kk < 16; ++kk) {
        float vp = bf16r(vf[kk] + posr[kk]);
        rr = fmaf(e[kk], vp, rr);
    }
    res[(size_t)bn * 256 + c] = bf16r(rr);
}

// ---------------------------------------------------------------------------
extern "C" void kernel_launch(void* const* d_in, const int* in_sizes, int n_in,
                              void* d_out, int out_size, void* d_ws, size_t ws_size,
                              hipStream_t stream)
{
    const float* xyz1     = (const float*)d_in[0];
    const float* points1  = (const float*)d_in[1];
    const float* xyz2     = (const float*)d_in[2];
    const float* points2  = (const float*)d_in[3];
    const float* up_w1    = (const float*)d_in[4];
    const float* up_b1    = (const float*)d_in[5];
    const float* up_w2    = (const float*)d_in[6];
    const float* up_b2    = (const float*)d_in[7];
    const float* fc1_w    = (const float*)d_in[8];
    const float* fc1_b    = (const float*)d_in[9];
    const float* fc2_w    = (const float*)d_in[10];
    const float* fc2_b    = (const float*)d_in[11];
    const float* delta_w1 = (const float*)d_in[12];
    const float* delta_b1 = (const float*)d_in[13];
    const float* delta_w2 = (const float*)d_in[14];
    const float* delta_b2 = (const float*)d_in[15];
    const float* gamma_w1 = (const float*)d_in[16];
    const float* gamma_b1 = (const float*)d_in[17];
    const float* gamma_w2 = (const float*)d_in[18];
    const float* gamma_b2 = (const float*)d_in[19];
    const float* wq       = (const float*)d_in[20];
    const float* wk       = (const float*)d_in[21];
    const float* wv       = (const float*)d_in[22];

    float* ws = (float*)d_ws;
    float* f1    = ws;
    float* feats = f1 + (size_t)BB * N1 * 256;
    float* x     = feats + (size_t)BB * N2 * 256;
    float* qb    = x + (size_t)BB * N2 * 256;
    float* kb    = qb + (size_t)BB * N2 * 256;
    float* vb    = kb + (size_t)BB * N2 * 256;
    int*   idx3  = (int*)(vb + (size_t)BB * N2 * 256);
    float* w3    = (float*)(idx3 + (size_t)BB * N2 * 3);
    int*   knn   = (int*)(w3 + (size_t)BB * N2 * 3);
    unsigned short* Bd2  = (unsigned short*)(knn + (size_t)BB * N2 * 16);
    unsigned short* Bg1  = Bd2 + 65536;
    unsigned short* Bg2  = Bg1 + 65536;
    unsigned short* Bup1 = Bg2 + 65536;       // 512x256 -> 131072
    unsigned short* Bup2 = Bup1 + 131072;
    unsigned short* Bfc1 = Bup2 + 65536;
    unsigned short* Bfc2 = Bfc1 + 65536;
    unsigned short* Bq   = Bfc2 + 65536;
    unsigned short* Bk   = Bq + 65536;
    unsigned short* Bv   = Bk + 65536;
    float* resb = x;   // x dead after q/k/v

    float* out = (float*)d_out;
    hipMemcpyAsync(out, xyz2, (size_t)BB * N2 * 3 * sizeof(float),
                   hipMemcpyDeviceToDevice, stream);

    const float BN = (float)(1.0 / sqrt(1.0 + 1e-5));

    // one-time weight swizzles
    swizzleW<<<64, 256, 0, stream>>>(up_w1, Bup1, CIN);
    swizzleW<<<32, 256, 0, stream>>>(up_w2, Bup2, CC);
    swizzleW<<<32, 256, 0, stream>>>(fc1_w, Bfc1, CC);
    swizzleW<<<32, 256, 0, stream>>>(fc2_w, Bfc2, CC);
    swizzleW<<<32, 256, 0, stream>>>(wq, Bq, CC);
    swizzleW<<<32, 256, 0, stream>>>(wk, Bk, CC);
    swizzleW<<<32, 256, 0, stream>>>(wv, Bv, CC);
    swizzleW<<<32, 256, 0, stream>>>(delta_w2, Bd2, CC);
    swizzleW<<<32, 256, 0, stream>>>(gamma_w1, Bg1, CC);
    swizzleW<<<32, 256, 0, stream>>>(gamma_w2, Bg2, CC);

    // f2 = relu(bf16(points2) @ bf16(up_w2) * bn) -> feats   [512 blocks]
    gemm_mfma<CC, 8, true, true, false><<<BB * N2 / 64 * 2, 256, 0, stream>>>(
        points2, Bup2, up_b2, nullptr, BN, feats);
    // f1 = relu(bf16(points1) @ bf16(up_w1) * bn)            [256 blocks]
    gemm_mfma<CIN, 4, true, true, false><<<BB * N1 / 64 * 4, 256, 0, stream>>>(
        points1, Bup1, up_b1, nullptr, BN, f1);
    // selection on raw fp32 coords (bit-identical)
    nn3_kernel<<<BB * 16, 256, 0, stream>>>(xyz1, xyz2, idx3, w3);
    interp_kernel<<<BB * N2, 256, 0, stream>>>(f1, idx3, w3, feats);
    // x = bf16r(feats @ bf16(fc1_w))                         [512 blocks]
    gemm_mfma<CC, 8, false, false, false><<<BB * N2 / 64 * 2, 256, 0, stream>>>(
        feats, Bfc1, fc1_b, nullptr, 1.f, x);
    // fused q/k/v                                            [512 blocks]
    qkv_mfma<<<BB * N2 / 64 * 2, 256, 0, stream>>>(x, Bq, Bk, Bv, qb, kb, vb);
    knn_kernel<<<BB * 64, 256, 0, stream>>>(xyz2, knn);
    attn_mfma<<<BB * N2, 256, 0, stream>>>(xyz2, qb, kb, vb, knn,
                                           delta_w1, delta_b1, delta_b2, gamma_b1, gamma_b2,
                                           Bd2, Bg1, Bg2, resb);
    // out1 = bf16r(bf16r(resb @ bf16(fc2_w)) + feats)        [512 blocks]
    gemm_mfma<CC, 8, false, false, true><<<BB * N2 / 64 * 2, 256, 0, stream>>>(
        resb, Bfc2, fc2_b, feats, 1.f, out + (size_t)BB * N2 * 3);
}